// Round 6
// baseline (3241.450 us; speedup 1.0000x reference)
//
#include <hip/hip_runtime.h>
#include <math.h>

#define B_    8
#define K_    8
#define C_    128
#define HW_   4096
#define NUM_  2048
#define N_    7          // K-1 refs used

// ---------------- workspace layout (floats) ----------------
#define WS_A_OFF    0
#define WS_INV_OFF  (B_*NUM_*C_)
#define WS_I1_OFF   (WS_INV_OFF + B_*K_*HW_)
#define WS_I2_OFF   (WS_I1_OFF + B_*N_*NUM_)

// ---- contraction-proof mul/add: the asm barrier makes the result opaque so
// the compiler cannot fuse the multiply into a following add (hipcc default
// is -ffp-contract=fast and WILL fuse plain a*b+c).
static __device__ __forceinline__ float fmul_nc(float a, float b) {
    float r = a * b;
    asm volatile("" : "+v"(r));
    return r;
}
static __device__ __forceinline__ float fadd_nc(float a, float b) {
    float r = a + b;
    asm volatile("" : "+v"(r));
    return r;
}

// ---------------------------------------------------------------------------
// Kernel 1: per-(b,k,h) inverse L2 norm over c (fp32 guide values for the
// fast GEMM pass only; final ordering decided by the emulation kernel).
// ---------------------------------------------------------------------------
__global__ void norm_kernel(const float* __restrict__ refs,
                            float* __restrict__ inv) {
    int i = blockIdx.x * blockDim.x + threadIdx.x;   // over B*K*HW
    int h  = i & (HW_ - 1);
    int bk = i >> 12;
    const float* p = refs + (size_t)bk * C_ * HW_ + h;
    float ss = 0.f;
#pragma unroll 8
    for (int c = 0; c < C_; ++c) {
        float v = p[(size_t)c * HW_];
        ss = fmaf(v, v, ss);
    }
    float n = sqrtf(ss);
    inv[i] = 1.0f / fmaxf(n, 1e-12f);
}

// ---------------------------------------------------------------------------
// Kernel 2: gather query vectors A[b][q][c] = feat[b][c][fi(b,q)].
// ---------------------------------------------------------------------------
__global__ void aprep_kernel(const float* __restrict__ feat,
                             const int* __restrict__ fidx,
                             float* __restrict__ A) {
    int i = blockIdx.x * blockDim.x + threadIdx.x;   // over B*NUM*C
    int c  = i & (C_ - 1);
    int bq = i >> 7;
    int fi = fidx[bq];
    int b  = bq >> 11;
    A[i] = feat[((size_t)b * C_ + c) * HW_ + fi];
}

// ---------------------------------------------------------------------------
// Kernel 3: per (b,n): S = A(2048x128) * B(128x4096)*invnorm; track TOP-2
// (value desc, index asc) per q. Tile BM=64 q, BN=64 h, K=128 LDS-resident.
// 256 threads, 4x4 regs/thread. fp32; winner decided by emulation kernel.
// ---------------------------------------------------------------------------
__global__ __launch_bounds__(256, 2) void gemm_argmax(
        const float* __restrict__ A, const float* __restrict__ refs,
        const float* __restrict__ inv, const int* __restrict__ pindex,
        int* __restrict__ i1out, int* __restrict__ i2out) {
    __shared__ float As[C_ * 68];    // [c][q], stride 68 (padded)
    __shared__ float Bs[C_ * 68];    // [c][h], stride 68 (padded)
    __shared__ float invs[64];

    int bid  = blockIdx.x;
    int pair = bid % 56;             // same (b,n) -> same XCD residue class
    int qt   = bid / 56;             // 0..31
    int b = pair / N_, n = pair % N_;
    int index = pindex[0];
    int ks = n + (n >= index ? 1 : 0);

    int tid = threadIdx.x;
    int col = tid & 15;              // h groups
    int row = tid >> 4;              // q groups
    int q0  = qt * 64;

    const float* Ab   = A    + ((size_t)b * NUM_ + q0) * C_;
    const float* Bb   = refs + (size_t)(b * K_ + ks) * C_ * HW_;
    const float* invb = inv  + (size_t)(b * K_ + ks) * HW_;

    // ---- load A tile, transposed into As[c][q] ----
#pragma unroll
    for (int i = 0; i < 8; ++i) {
        int f4 = tid + i * 256;              // 0..2047
        int q  = f4 >> 5;
        int c4 = (f4 & 31) << 2;
        float4 v = *reinterpret_cast<const float4*>(Ab + q * C_ + c4);
        As[(c4 + 0) * 68 + q] = v.x;
        As[(c4 + 1) * 68 + q] = v.y;
        As[(c4 + 2) * 68 + q] = v.z;
        As[(c4 + 3) * 68 + q] = v.w;
    }

    // ---- prologue: load h-tile 0 of B + invnorm into regs, then LDS ----
    const int hc = (tid & 15) << 2;          // h offset within tile (0..60)
    const int cr = tid >> 4;                 // c row base (0..15), step 16
    float4 pre[8];
    float4 ivn;
#pragma unroll
    for (int i = 0; i < 8; ++i) {
        int c = cr + i * 16;
        pre[i] = *reinterpret_cast<const float4*>(Bb + (size_t)c * HW_ + hc);
    }
    if (tid < 16) ivn = *reinterpret_cast<const float4*>(invb + (tid << 2));

#pragma unroll
    for (int i = 0; i < 8; ++i) {
        int c = cr + i * 16;
        *reinterpret_cast<float4*>(&Bs[c * 68 + hc]) = pre[i];
    }
    if (tid < 16) *reinterpret_cast<float4*>(&invs[tid << 2]) = ivn;
    __syncthreads();

    float best[4], secd[4];
    int   bidx[4], sidx[4];
#pragma unroll
    for (int i = 0; i < 4; ++i) {
        best[i] = -INFINITY; bidx[i] = 0;
        secd[i] = -INFINITY; sidx[i] = 0;
    }

    for (int t = 0; t < 64; ++t) {
        // prefetch next h-tile into registers (latency hidden by k-loop)
        float4 nxt[8]; float4 ivn2;
        if (t + 1 < 64) {
            int h0 = (t + 1) * 64;
#pragma unroll
            for (int i = 0; i < 8; ++i) {
                int c = cr + i * 16;
                nxt[i] = *reinterpret_cast<const float4*>(
                    Bb + (size_t)c * HW_ + h0 + hc);
            }
            if (tid < 16)
                ivn2 = *reinterpret_cast<const float4*>(invb + h0 + (tid << 2));
        }

        // ---- k-loop: 128 steps, 16 FMA each ----
        float acc[4][4];
#pragma unroll
        for (int i = 0; i < 4; ++i)
#pragma unroll
            for (int j = 0; j < 4; ++j) acc[i][j] = 0.f;

#pragma unroll 4
        for (int k = 0; k < C_; ++k) {
            float4 a4 = *reinterpret_cast<const float4*>(&As[k * 68 + (row << 2)]);
            float4 b4 = *reinterpret_cast<const float4*>(&Bs[k * 68 + (col << 2)]);
            float ar[4] = {a4.x, a4.y, a4.z, a4.w};
            float br[4] = {b4.x, b4.y, b4.z, b4.w};
#pragma unroll
            for (int i = 0; i < 4; ++i)
#pragma unroll
                for (int j = 0; j < 4; ++j)
                    acc[i][j] = fmaf(ar[i], br[j], acc[i][j]);
        }

        // ---- epilogue: scale by invnorm, running TOP-2 (ascending h) ----
        int hbase = t * 64 + (col << 2);
#pragma unroll
        for (int j = 0; j < 4; ++j) {
            float iv = invs[(col << 2) + j];
            int   h  = hbase + j;
#pragma unroll
            for (int i = 0; i < 4; ++i) {
                float s = acc[i][j] * iv;
                if (s > best[i]) {
                    secd[i] = best[i]; sidx[i] = bidx[i];
                    best[i] = s;       bidx[i] = h;
                } else if (s > secd[i]) {
                    secd[i] = s;       sidx[i] = h;
                }
            }
        }

        __syncthreads();
        if (t + 1 < 64) {
#pragma unroll
            for (int i = 0; i < 8; ++i) {
                int c = cr + i * 16;
                *reinterpret_cast<float4*>(&Bs[c * 68 + hc]) = nxt[i];
            }
            if (tid < 16) *reinterpret_cast<float4*>(&invs[tid << 2]) = ivn2;
        }
        __syncthreads();
    }

    // ---- merge top-2 lists across the 16 h-columns sharing each q ----
#pragma unroll
    for (int i = 0; i < 4; ++i) {
        float v1 = best[i], v2 = secd[i];
        int   x1 = bidx[i], x2 = sidx[i];
#pragma unroll
        for (int off = 1; off < 16; off <<= 1) {
            float w1 = __shfl_xor(v1, off), w2 = __shfl_xor(v2, off);
            int   y1 = __shfl_xor(x1, off), y2 = __shfl_xor(x2, off);
            bool pfirst = (v1 > w1) || (v1 == w1 && x1 <= y1);
            float nv1, nv2; int nx1, nx2;
            if (pfirst) {
                nv1 = v1; nx1 = x1;
                bool t2 = (w1 > v2) || (w1 == v2 && y1 < x2);
                nv2 = t2 ? w1 : v2; nx2 = t2 ? y1 : x2;
            } else {
                nv1 = w1; nx1 = y1;
                bool t2 = (v1 > w2) || (v1 == w2 && x1 < y2);
                nv2 = t2 ? v1 : w2; nx2 = t2 ? x1 : y2;
            }
            v1 = nv1; x1 = nx1; v2 = nv2; x2 = nx2;
        }
        if (col == 0) {
            int q = q0 + (row << 2) + i;
            size_t o = (size_t)(b * N_ + n) * NUM_ + q;
            i1out[o] = x1;
            i2out[o] = x2;
        }
    }
}

// ---------------------------------------------------------------------------
// numpy pairwise sum (n=128, blocksize path): 8 accumulators unrolled, then
// ((r0+r1)+(r2+r3)) + ((r4+r5)+(r6+r7)). Used for the query norms; their
// rounding cancels between the two candidates anyway (shared w2 vector).
// ---------------------------------------------------------------------------
static __device__ float pairwise128_sumsq_div(const float* __restrict__ x,
                                              float d) {
    float r[8];
#pragma unroll
    for (int j = 0; j < 8; ++j) {
        float v = __fdiv_rn(x[j], d);
        r[j] = fmul_nc(v, v);
    }
    for (int i = 8; i < C_; i += 8) {
#pragma unroll
        for (int j = 0; j < 8; ++j) {
            float v = __fdiv_rn(x[i + j], d);
            r[j] = fadd_nc(r[j], fmul_nc(v, v));
        }
    }
    return fadd_nc(fadd_nc(fadd_nc(r[0], r[1]), fadd_nc(r[2], r[3])),
                   fadd_nc(fadd_nc(r[4], r[5]), fadd_nc(r[6], r[7])));
}

// ---------------------------------------------------------------------------
// Emulated numpy score for candidate column h — EVERYTHING non-FMA:
//   ref-col norm: sq temp + add.reduce, sequential ascending-c (hw is the
//                 vectorized inner dim; per-h rounding is scalar sequential)
//   dot: np.einsum sum-of-products, out[h] += w2[c]*wr[c][h] — sequential
//        ascending-c, separate SSE mul+add (NO FMA in einsum loops)
// ---------------------------------------------------------------------------
static __device__ float emul_score(const float* __restrict__ qp,
                                   const float* __restrict__ Rb,
                                   int h, float n1, float n2) {
    float rv0 = Rb[h];
    float sr = fmul_nc(rv0, rv0);
    for (int c = 1; c < C_; ++c) {
        float rv = Rb[(size_t)c * HW_ + h];
        sr = fadd_nc(sr, fmul_nc(rv, rv));    // non-FMA, ascending c
    }
    float nr = fmaxf(__fsqrt_rn(sr), 1e-12f);
    float acc = 0.f;
    for (int c = 0; c < C_; ++c) {
        float w2 = __fdiv_rn(__fdiv_rn(qp[c], n1), n2);
        float wr = __fdiv_rn(Rb[(size_t)c * HW_ + h], nr);
        acc = fadd_nc(acc, fmul_nc(w2, wr));  // non-FMA, ascending c
    }
    return acc;
}

// ---------------------------------------------------------------------------
// Kernel 3b: adjudicate the fp32-GEMM top-2 by emulating numpy's own fp32
// arithmetic. Strict > with lower-index-on-equality = numpy argmax.
// One thread per (b,n,q) row.
// ---------------------------------------------------------------------------
__global__ void rescore_emul(const float* __restrict__ A,
                             const float* __restrict__ refs,
                             const int* __restrict__ pindex,
                             const int* __restrict__ i1buf,
                             const int* __restrict__ i2buf,
                             int* __restrict__ idxout,
                             float* __restrict__ out2) {
    int r = blockIdx.x * blockDim.x + threadIdx.x;   // over B*N*NUM
    if (r >= B_ * N_ * NUM_) return;
    int q  = r & (NUM_ - 1);
    int bn = r >> 11;
    int b = bn / N_, n = bn % N_;
    int index = pindex[0];
    int ks = n + (n >= index ? 1 : 0);
    int ia = i1buf[r], ib = i2buf[r];

    const float* qp = A    + ((size_t)b * NUM_ + q) * C_;
    const float* Rb = refs + (size_t)(b * K_ + ks) * C_ * HW_;

    // query norms (shared by both candidates; rounding cancels in compare)
    float s1 = pairwise128_sumsq_div(qp, 1.0f);
    float n1 = fmaxf(__fsqrt_rn(s1), 1e-12f);
    float s2 = pairwise128_sumsq_div(qp, n1);
    float n2 = fmaxf(__fsqrt_rn(s2), 1e-12f);

    float sa = emul_score(qp, Rb, ia, n1, n2);
    float sb = emul_score(qp, Rb, ib, n1, n2);

    int lo_i, hi_i; float lo_s, hi_s;
    if (ia < ib) { lo_i = ia; lo_s = sa; hi_i = ib; hi_s = sb; }
    else         { lo_i = ib; lo_s = sb; hi_i = ia; hi_s = sa; }
    // argmax: later index wins only on STRICT greater
    int win = (hi_s > lo_s) ? hi_i : lo_i;
    idxout[r] = win;
    out2[r]   = (float)win;
}

// ---------------------------------------------------------------------------
// Kernel 4: fused = base_sim*feat_sel + sum_n sims[n]*refs[b,kn,:,idx_n],
// scattered into out[b][c][fi]. Also writes feat_indices output as float.
// ---------------------------------------------------------------------------
__global__ void fuse_scatter(const float* __restrict__ A,
                             const float* __restrict__ refs,
                             const float* __restrict__ sim,
                             const int* __restrict__ fidx,
                             const int* __restrict__ pindex,
                             const int* __restrict__ idxbuf,
                             float* __restrict__ out0,
                             float* __restrict__ out1) {
    int bq = blockIdx.x;                 // over B*NUM
    int q  = bq & (NUM_ - 1);
    int b  = bq >> 11;
    int c  = threadIdx.x;                // 128 threads
    int index = pindex[0];
    int fi = fidx[bq];

    float v = sim[b * K_ + index] * A[(size_t)bq * C_ + c];
#pragma unroll
    for (int n = 0; n < N_; ++n) {
        int ks = n + (n >= index ? 1 : 0);
        int id = idxbuf[(size_t)(b * N_ + n) * NUM_ + q];
        v = fmaf(sim[b * K_ + ks],
                 refs[((size_t)(b * K_ + ks) * C_ + c) * HW_ + id], v);
    }
    out0[((size_t)b * C_ + c) * HW_ + fi] = v;
    if (c == 0) out1[bq] = (float)fi;
}

// ---------------------------------------------------------------------------
extern "C" void kernel_launch(void* const* d_in, const int* in_sizes, int n_in,
                              void* d_out, int out_size, void* d_ws, size_t ws_size,
                              hipStream_t stream) {
    const float* feat = (const float*)d_in[0];   // [B][C][HW]
    const float* refs = (const float*)d_in[1];   // [B][K][C][HW]
    const float* sim  = (const float*)d_in[2];   // [B][K]
    const int*   fidx = (const int*)d_in[3];     // [B][NUM]
    const int*   pidx = (const int*)d_in[4];     // scalar index

    float* wsf   = (float*)d_ws;
    float* A     = wsf + WS_A_OFF;
    float* inv   = wsf + WS_INV_OFF;
    int*   i1buf = (int*)(wsf + WS_I1_OFF);
    int*   i2buf = (int*)(wsf + WS_I2_OFF);

    float* out0 = (float*)d_out;                       // [B][C][HW]
    float* out1 = out0 + (size_t)B_ * C_ * HW_;        // feat_indices (f32)
    float* out2 = out1 + (size_t)B_ * NUM_;            // ref_indices (f32)
    int*   idxf = (int*)i1buf;                         // final idx reuses i1

    // inverse norms of all ref columns
    norm_kernel<<<(B_ * K_ * HW_) / 256, 256, 0, stream>>>(refs, inv);
    // gather raw query vectors
    aprep_kernel<<<(B_ * NUM_ * C_) / 256, 256, 0, stream>>>(feat, fidx, A);
    // out0 = feat (then scatter overwrites selected columns)
    hipMemcpyAsync(out0, feat, (size_t)B_ * C_ * HW_ * sizeof(float),
                   hipMemcpyDeviceToDevice, stream);
    // GEMM + top-2: 56 (b,n) pairs x 32 q-tiles
    gemm_argmax<<<56 * 32, 256, 0, stream>>>(A, refs, inv, pidx, i1buf, i2buf);
    // numpy-emulating adjudication of top-2
    rescore_emul<<<(B_ * N_ * NUM_ + 255) / 256, 256, 0, stream>>>(
        A, refs, pidx, i1buf, i2buf, idxf, out2);
    // fused gather + scatter
    fuse_scatter<<<B_ * NUM_, 128, 0, stream>>>(A, refs, sim, fidx, pidx,
                                                idxf, out0, out1);
}

// Round 7
// 1517.996 us; speedup vs baseline: 2.1353x; 2.1353x over previous
//
#include <hip/hip_runtime.h>
#include <math.h>

#define B_    8
#define K_    8
#define C_    128
#define HW_   4096
#define NUM_  2048
#define N_    7          // K-1 refs used

// ---------------- workspace layout (32-bit words) ----------------
#define WS_A_OFF    0                               // [B][NUM][C] floats
#define WS_INV_OFF  (B_*NUM_*C_)                    // [B][K][HW] floats
#define WS_CAND_OFF (WS_INV_OFF + B_*K_*HW_)        // [B][N][NUM] int4
#define WS_GAP_OFF  (WS_CAND_OFF + B_*N_*NUM_*4)    // [B][N][NUM] float
#define WS_IDX_OFF  (WS_GAP_OFF + B_*N_*NUM_)       // [B][N][NUM] int

typedef __bf16 bf16x8 __attribute__((ext_vector_type(8)));
typedef float  f32x4  __attribute__((ext_vector_type(4)));
typedef unsigned int u32x4 __attribute__((ext_vector_type(4)));

static __device__ __forceinline__ f32x4 mf16(bf16x8 a, bf16x8 b, f32x4 c) {
    return __builtin_amdgcn_mfma_f32_16x16x32_bf16(a, b, c, 0, 0, 0);
}

// RTNE bf16 high-part (bit math, branch-free)
static __device__ __forceinline__ unsigned bfhi16(float x) {
    unsigned b = __float_as_uint(x);
    return (b + 0x7fffu + ((b >> 16) & 1u)) >> 16;
}
// split two floats (consecutive k) into packed hi-pair and lo-pair u32
static __device__ __forceinline__ void split2(float x, float y,
                                              unsigned &hp, unsigned &lp) {
    unsigned hx = bfhi16(x), hy = bfhi16(y);
    float rx = x - __uint_as_float(hx << 16);
    float ry = y - __uint_as_float(hy << 16);
    hp = hx | (hy << 16);
    lp = bfhi16(rx) | (bfhi16(ry) << 16);
}

// ---- contraction-proof mul/add (verbatim from the passing round-6 kernel)
static __device__ __forceinline__ float fmul_nc(float a, float b) {
    float r = a * b;
    asm volatile("" : "+v"(r));
    return r;
}
static __device__ __forceinline__ float fadd_nc(float a, float b) {
    float r = a + b;
    asm volatile("" : "+v"(r));
    return r;
}

// ---------------------------------------------------------------------------
// Kernel 1: per-(b,k,h) inverse L2 norm over c (fast fp32 guide values; used
// only to scale split-GEMM scores — final near-ties decided by emulation).
// ---------------------------------------------------------------------------
__global__ void norm_kernel(const float* __restrict__ refs,
                            float* __restrict__ inv) {
    int i = blockIdx.x * blockDim.x + threadIdx.x;   // over B*K*HW
    int h  = i & (HW_ - 1);
    int bk = i >> 12;
    const float* p = refs + (size_t)bk * C_ * HW_ + h;
    float ss = 0.f;
#pragma unroll 8
    for (int c = 0; c < C_; ++c) {
        float v = p[(size_t)c * HW_];
        ss = fmaf(v, v, ss);
    }
    inv[i] = 1.0f / fmaxf(sqrtf(ss), 1e-12f);
}

// ---------------------------------------------------------------------------
// Kernel 2: gather query vectors A[b][q][c] = feat[b][c][fi(b,q)].
// ---------------------------------------------------------------------------
__global__ void aprep_kernel(const float* __restrict__ feat,
                             const int* __restrict__ fidx,
                             float* __restrict__ A) {
    int i = blockIdx.x * blockDim.x + threadIdx.x;   // over B*NUM*C
    int c  = i & (C_ - 1);
    int bq = i >> 7;
    int fi = fidx[bq];
    int b  = bq >> 11;
    A[i] = feat[((size_t)b * C_ + c) * HW_ + fi];
}

// ---------------------------------------------------------------------------
// Kernel 3: split-bf16 4-pass MFMA GEMM + exact top-4 (of split scores).
// Per (b,n): S = A(2048x128) x B(128x4096) * invnorm[h].
// Block: 256 thr (4 waves), tile 128q x 32h per iter, K=128 in A-registers.
// B staged in LDS as interleaved (hiPair|loPair) u32, stride-132 rows, dbuf.
// ---------------------------------------------------------------------------
__global__ __launch_bounds__(256, 2) void gemm_split_topk(
        const float* __restrict__ A, const float* __restrict__ refs,
        const float* __restrict__ inv, const int* __restrict__ pindex,
        int4* __restrict__ cand4, float* __restrict__ gaps) {
    __shared__ unsigned Bsh[2][32 * 132];   // 33,792 B

    const int tid = threadIdx.x;
    const int l = tid & 63, wq = tid >> 6;
    const int ll = l & 15, lh = l >> 4;

    // XCD swizzle: 112 consecutive work-ids (7 pairs x 16 q-tiles) per XCD
    int bid = blockIdx.x;
    int swz = (bid & 7) * 112 + (bid >> 3);
    int pair = swz >> 4, qt = swz & 15;
    int b = pair / N_, n = pair % N_;
    int index = pindex[0];
    int ks = n + (n >= index ? 1 : 0);

    const float* Ap   = A    + ((size_t)b * NUM_ + qt * 128 + wq * 32) * C_;
    const float* Bb   = refs + (size_t)(b * K_ + ks) * C_ * HW_;
    const float* invb = inv  + (size_t)(b * K_ + ks) * HW_;

    // ---- A fragments (hi/lo split), persistent in registers ----
    bf16x8 ahi[2][4], alo[2][4];
#pragma unroll
    for (int mf = 0; mf < 2; ++mf)
#pragma unroll
        for (int kk = 0; kk < 4; ++kk) {
            const float* ap = Ap + (mf * 16 + ll) * C_ + kk * 32 + lh * 8;
            float4 xa = *(const float4*)ap;
            float4 xb = *(const float4*)(ap + 4);
            float xs[8] = {xa.x, xa.y, xa.z, xa.w, xb.x, xb.y, xb.z, xb.w};
            u32x4 H, L;
#pragma unroll
            for (int p = 0; p < 4; ++p) {
                unsigned hp, lp;
                split2(xs[2*p], xs[2*p+1], hp, lp);
                H[p] = hp; L[p] = lp;
            }
            ahi[mf][kk] = __builtin_bit_cast(bf16x8, H);
            alo[mf][kk] = __builtin_bit_cast(bf16x8, L);
        }

    // ---- per-lane running top-2 per q-row (8 rows: 2 mf x 4 reg) ----
    float tv1[8], tv2[8]; int ti1[8], ti2[8];
#pragma unroll
    for (int rw = 0; rw < 8; ++rw) {
        tv1[rw] = -INFINITY; tv2[rw] = -INFINITY;
        ti1[rw] = 0; ti2[rw] = 0;
    }

    // ---- staging map: tile = 32h x 128c; thread: 4h x 2c-pairs ----
    const int hq = tid & 7, h0 = hq * 4;
    const int cp = tid >> 3;            // 0..31
    float4 ldr[4];

    // prologue: load tile 0
#pragma unroll
    for (int i = 0; i < 2; ++i) {
        int c = 2 * cp + 64 * i;
        ldr[2*i]   = *(const float4*)(Bb + (size_t)c * HW_ + h0);
        ldr[2*i+1] = *(const float4*)(Bb + (size_t)(c + 1) * HW_ + h0);
    }

    for (int t = 0; t < 128; ++t) {
        const int cur = t & 1;
        const int ht = t * 32;

        // write tile t into Bsh[cur]
#pragma unroll
        for (int i = 0; i < 2; ++i) {
            int c = 2 * cp + 64 * i;
            int g8 = c >> 3;
            int pw = cp & 3;
            float a0[4] = {ldr[2*i].x,   ldr[2*i].y,   ldr[2*i].z,   ldr[2*i].w};
            float a1[4] = {ldr[2*i+1].x, ldr[2*i+1].y, ldr[2*i+1].z, ldr[2*i+1].w};
#pragma unroll
            for (int j = 0; j < 4; ++j) {
                unsigned hp, lp;
                split2(a0[j], a1[j], hp, lp);
                int base = (h0 + j) * 132 + g8 * 8;
                Bsh[cur][base + pw]     = hp;
                Bsh[cur][base + 4 + pw] = lp;
            }
        }
        // issue global loads for tile t+1 (latency hides under MFMA below)
        if (t < 127) {
            int ht1 = ht + 32;
#pragma unroll
            for (int i = 0; i < 2; ++i) {
                int c = 2 * cp + 64 * i;
                ldr[2*i]   = *(const float4*)(Bb + (size_t)c * HW_ + ht1 + h0);
                ldr[2*i+1] = *(const float4*)(Bb + (size_t)(c + 1) * HW_ + ht1 + h0);
            }
        }
        __syncthreads();   // tile t visible to all waves

        // ---- 4-pass MFMA: acc = Ah*Bh + Ah*Bl + Al*Bh + Al*Bl ----
        f32x4 acc[2][2];
#pragma unroll
        for (int mf = 0; mf < 2; ++mf)
#pragma unroll
            for (int nf = 0; nf < 2; ++nf) acc[mf][nf] = 0.f;

#pragma unroll
        for (int kk = 0; kk < 4; ++kk) {
#pragma unroll
            for (int nf = 0; nf < 2; ++nf) {
                int base = (nf * 16 + ll) * 132 + (kk * 4 + lh) * 8;
                u32x4 bhu = *(const u32x4*)&Bsh[cur][base];
                u32x4 blu = *(const u32x4*)&Bsh[cur][base + 4];
                bf16x8 bh = __builtin_bit_cast(bf16x8, bhu);
                bf16x8 bl = __builtin_bit_cast(bf16x8, blu);
#pragma unroll
                for (int mf = 0; mf < 2; ++mf) {
                    f32x4 a_ = acc[mf][nf];
                    a_ = mf16(ahi[mf][kk], bh, a_);
                    a_ = mf16(ahi[mf][kk], bl, a_);
                    a_ = mf16(alo[mf][kk], bh, a_);
                    a_ = mf16(alo[mf][kk], bl, a_);
                    acc[mf][nf] = a_;
                }
            }
        }

        // ---- scale by invnorm, running top-2 (h ascending) ----
        float iv0 = invb[ht + ll];
        float iv1 = invb[ht + 16 + ll];
#pragma unroll
        for (int mf = 0; mf < 2; ++mf)
#pragma unroll
            for (int r = 0; r < 4; ++r) {
                int rw = mf * 4 + r;
#pragma unroll
                for (int nf = 0; nf < 2; ++nf) {
                    float s = acc[mf][nf][r] * (nf ? iv1 : iv0);
                    int h = ht + nf * 16 + ll;
                    if (s > tv1[rw]) {
                        tv2[rw] = tv1[rw]; ti2[rw] = ti1[rw];
                        tv1[rw] = s;       ti1[rw] = h;
                    } else if (s > tv2[rw]) {
                        tv2[rw] = s; ti2[rw] = h;
                    }
                }
            }
        // single barrier per iter is sufficient (buffers alternate; all waves
        // complete compute(t) before any wave's write(t+2) — barrier(t+1)
        // orders it)
    }

    // ---- 16-lane bitonic merge of per-lane top-2 lists -> global top-4 ----
#define CE(X,Y) { bool sw_ = (mv[Y] > mv[X]) || (mv[Y] == mv[X] && mi[Y] < mi[X]); \
                  if (sw_) { float tf_ = mv[X]; mv[X] = mv[Y]; mv[Y] = tf_;       \
                             int   td_ = mi[X]; mi[X] = mi[Y]; mi[Y] = td_; } }
#pragma unroll
    for (int rw = 0; rw < 8; ++rw) {
        float av[4] = {tv1[rw], tv2[rw], -INFINITY, -INFINITY};
        int   ai[4] = {ti1[rw], ti2[rw], 0x7fffffff, 0x7fffffff};
#pragma unroll
        for (int s = 1; s <= 8; s <<= 1) {
            float bv[4]; int bi[4];
#pragma unroll
            for (int j = 0; j < 4; ++j) {
                bv[j] = __shfl_xor(av[j], s);
                bi[j] = __shfl_xor(ai[j], s);
            }
            float mv[4]; int mi[4];
#pragma unroll
            for (int j = 0; j < 4; ++j) {   // bitonic keep-top4
                bool ta = (av[j] > bv[3-j]) ||
                          (av[j] == bv[3-j] && ai[j] < bi[3-j]);
                mv[j] = ta ? av[j] : bv[3-j];
                mi[j] = ta ? ai[j] : bi[3-j];
            }
            CE(0, 2) CE(1, 3) CE(0, 1) CE(2, 3)
#pragma unroll
            for (int j = 0; j < 4; ++j) { av[j] = mv[j]; ai[j] = mi[j]; }
        }
        if (ll == 0) {
            int q = qt * 128 + wq * 32 + (rw >> 2) * 16 + lh * 4 + (rw & 3);
            size_t o = (size_t)(b * N_ + n) * NUM_ + q;
            cand4[o] = make_int4(ai[0], ai[1], ai[2], ai[3]);
            gaps[o]  = av[0] - av[1];
        }
    }
#undef CE
}

// ---------------------------------------------------------------------------
// numpy pairwise sum (n=128): 8 accumulators then pairwise combine. Verbatim
// from the passing round-6 kernel.
// ---------------------------------------------------------------------------
static __device__ float pairwise128_sumsq_div(const float* __restrict__ x,
                                              float d) {
    float r[8];
#pragma unroll
    for (int j = 0; j < 8; ++j) {
        float v = __fdiv_rn(x[j], d);
        r[j] = fmul_nc(v, v);
    }
    for (int i = 8; i < C_; i += 8) {
#pragma unroll
        for (int j = 0; j < 8; ++j) {
            float v = __fdiv_rn(x[i + j], d);
            r[j] = fadd_nc(r[j], fmul_nc(v, v));
        }
    }
    return fadd_nc(fadd_nc(fadd_nc(r[0], r[1]), fadd_nc(r[2], r[3])),
                   fadd_nc(fadd_nc(r[4], r[5]), fadd_nc(r[6], r[7])));
}

// Emulated numpy score (verbatim from round 6 — all non-FMA where numpy is).
static __device__ float emul_score(const float* __restrict__ qp,
                                   const float* __restrict__ Rb,
                                   int h, float n1, float n2) {
    float rv0 = Rb[h];
    float sr = fmul_nc(rv0, rv0);
    for (int c = 1; c < C_; ++c) {
        float rv = Rb[(size_t)c * HW_ + h];
        sr = fadd_nc(sr, fmul_nc(rv, rv));
    }
    float nr = fmaxf(__fsqrt_rn(sr), 1e-12f);
    float acc = 0.f;
    for (int c = 0; c < C_; ++c) {
        float w2 = __fdiv_rn(__fdiv_rn(qp[c], n1), n2);
        float wr = __fdiv_rn(Rb[(size_t)c * HW_ + h], nr);
        acc = fadd_nc(acc, fmul_nc(w2, wr));
    }
    return acc;
}

// ---------------------------------------------------------------------------
// Kernel 3b: adjudicate split-GEMM top-4. Prune when split gap is decisive
// (>3e-5 >> ~2e-6 total split+scale error); else exact numpy emulation of
// all 4 candidates with lowest-index tie-break.
// ---------------------------------------------------------------------------
__global__ void rescore_emul4(const float* __restrict__ A,
                              const float* __restrict__ refs,
                              const int* __restrict__ pindex,
                              const int4* __restrict__ cand4,
                              const float* __restrict__ gaps,
                              int* __restrict__ idxout,
                              float* __restrict__ out2) {
    int r = blockIdx.x * blockDim.x + threadIdx.x;   // over B*N*NUM
    if (r >= B_ * N_ * NUM_) return;
    int4 cd = cand4[r];
    int win;
    if (gaps[r] > 3e-5f) {
        win = cd.x;
    } else {
        int q  = r & (NUM_ - 1);
        int bn = r >> 11;
        int b = bn / N_, n = bn % N_;
        int index = pindex[0];
        int ks = n + (n >= index ? 1 : 0);
        const float* qp = A    + ((size_t)b * NUM_ + q) * C_;
        const float* Rb = refs + (size_t)(b * K_ + ks) * C_ * HW_;
        float s1 = pairwise128_sumsq_div(qp, 1.0f);
        float n1 = fmaxf(__fsqrt_rn(s1), 1e-12f);
        float s2 = pairwise128_sumsq_div(qp, n1);
        float n2 = fmaxf(__fsqrt_rn(s2), 1e-12f);
        float sa = emul_score(qp, Rb, cd.x, n1, n2);
        float sb = emul_score(qp, Rb, cd.y, n1, n2);
        float sc = emul_score(qp, Rb, cd.z, n1, n2);
        float sd = emul_score(qp, Rb, cd.w, n1, n2);
        win = cd.x; float bw = sa;
        if (sb > bw || (sb == bw && cd.y < win)) { bw = sb; win = cd.y; }
        if (sc > bw || (sc == bw && cd.z < win)) { bw = sc; win = cd.z; }
        if (sd > bw || (sd == bw && cd.w < win)) { bw = sd; win = cd.w; }
    }
    idxout[r] = win;
    out2[r]   = (float)win;
}

// ---------------------------------------------------------------------------
// Kernel 4: fused = base_sim*feat_sel + sum_n sims[n]*refs[b,kn,:,idx_n],
// scattered into out[b][c][fi]. Also writes feat_indices output as float.
// ---------------------------------------------------------------------------
__global__ void fuse_scatter(const float* __restrict__ A,
                             const float* __restrict__ refs,
                             const float* __restrict__ sim,
                             const int* __restrict__ fidx,
                             const int* __restrict__ pindex,
                             const int* __restrict__ idxbuf,
                             float* __restrict__ out0,
                             float* __restrict__ out1) {
    int bq = blockIdx.x;                 // over B*NUM
    int q  = bq & (NUM_ - 1);
    int b  = bq >> 11;
    int c  = threadIdx.x;                // 128 threads
    int index = pindex[0];
    int fi = fidx[bq];

    float v = sim[b * K_ + index] * A[(size_t)bq * C_ + c];
#pragma unroll
    for (int n = 0; n < N_; ++n) {
        int ks = n + (n >= index ? 1 : 0);
        int id = idxbuf[(size_t)(b * N_ + n) * NUM_ + q];
        v = fmaf(sim[b * K_ + ks],
                 refs[((size_t)(b * K_ + ks) * C_ + c) * HW_ + id], v);
    }
    out0[((size_t)b * C_ + c) * HW_ + fi] = v;
    if (c == 0) out1[bq] = (float)fi;
}

// ---------------------------------------------------------------------------
extern "C" void kernel_launch(void* const* d_in, const int* in_sizes, int n_in,
                              void* d_out, int out_size, void* d_ws, size_t ws_size,
                              hipStream_t stream) {
    const float* feat = (const float*)d_in[0];   // [B][C][HW]
    const float* refs = (const float*)d_in[1];   // [B][K][C][HW]
    const float* sim  = (const float*)d_in[2];   // [B][K]
    const int*   fidx = (const int*)d_in[3];     // [B][NUM]
    const int*   pidx = (const int*)d_in[4];     // scalar index

    float* wsf   = (float*)d_ws;
    float* A     = wsf + WS_A_OFF;
    float* inv   = wsf + WS_INV_OFF;
    int4*  cand  = (int4*)(wsf + WS_CAND_OFF);
    float* gaps  = wsf + WS_GAP_OFF;
    int*   idxf  = (int*)(wsf + WS_IDX_OFF);

    float* out0 = (float*)d_out;                       // [B][C][HW]
    float* out1 = out0 + (size_t)B_ * C_ * HW_;        // feat_indices (f32)
    float* out2 = out1 + (size_t)B_ * NUM_;            // ref_indices (f32)

    // inverse norms of all ref columns
    norm_kernel<<<(B_ * K_ * HW_) / 256, 256, 0, stream>>>(refs, inv);
    // gather raw query vectors
    aprep_kernel<<<(B_ * NUM_ * C_) / 256, 256, 0, stream>>>(feat, fidx, A);
    // out0 = feat (scatter overwrites selected columns later)
    hipMemcpyAsync(out0, feat, (size_t)B_ * C_ * HW_ * sizeof(float),
                   hipMemcpyDeviceToDevice, stream);
    // split-bf16 MFMA GEMM + top-4: 56 pairs x 16 q-tiles
    gemm_split_topk<<<56 * 16, 256, 0, stream>>>(A, refs, inv, pidx,
                                                 cand, gaps);
    // adjudication (pruned; exact numpy emulation on near-ties)
    rescore_emul4<<<(B_ * N_ * NUM_ + 255) / 256, 256, 0, stream>>>(
        A, refs, pidx, cand, gaps, idxf, out2);
    // fused gather + scatter
    fuse_scatter<<<B_ * NUM_, 128, 0, stream>>>(A, refs, sim, fidx, pidx,
                                                idxf, out0, out1);
}

// Round 8
// 1416.191 us; speedup vs baseline: 2.2889x; 1.0719x over previous
//
#include <hip/hip_runtime.h>
#include <math.h>

#define B_    8
#define K_    8
#define C_    128
#define HW_   4096
#define NUM_  2048
#define N_    7          // K-1 refs used

// ---------------- workspace layout (32-bit words) ----------------
#define WS_A_OFF    0                               // [B][NUM][C] floats
#define WS_INV_OFF  (B_*NUM_*C_)                    // [B][K][HW] floats
#define WS_CAND_OFF (WS_INV_OFF + B_*K_*HW_)        // [B][N][NUM] int4
#define WS_GAP_OFF  (WS_CAND_OFF + B_*N_*NUM_*4)    // [B][N][NUM] float
#define WS_IDX_OFF  (WS_GAP_OFF + B_*N_*NUM_)       // [B][N][NUM] int
#define WS_GHI_OFF  (WS_IDX_OFF + B_*N_*NUM_)       // pre-split planes
#define GPLANE_V4   (B_*K_*16*HW_)                  // u32x4 per plane

typedef __bf16 bf16x8 __attribute__((ext_vector_type(8)));
typedef float  f32x4  __attribute__((ext_vector_type(4)));
typedef unsigned int u32x4 __attribute__((ext_vector_type(4)));

static __device__ __forceinline__ f32x4 mf16(bf16x8 a, bf16x8 b, f32x4 c) {
    return __builtin_amdgcn_mfma_f32_16x16x32_bf16(a, b, c, 0, 0, 0);
}

// RTNE bf16 high-part (bit math, branch-free)
static __device__ __forceinline__ unsigned bfhi16(float x) {
    unsigned b = __float_as_uint(x);
    return (b + 0x7fffu + ((b >> 16) & 1u)) >> 16;
}
// split two floats (consecutive c) into packed hi-pair and lo-pair u32
static __device__ __forceinline__ void split2(float x, float y,
                                              unsigned &hp, unsigned &lp) {
    unsigned hx = bfhi16(x), hy = bfhi16(y);
    float rx = x - __uint_as_float(hx << 16);
    float ry = y - __uint_as_float(hy << 16);
    hp = hx | (hy << 16);
    lp = bfhi16(rx) | (bfhi16(ry) << 16);
}

// ---- contraction-proof mul/add (verbatim from the passing round-6 kernel)
static __device__ __forceinline__ float fmul_nc(float a, float b) {
    float r = a * b;
    asm volatile("" : "+v"(r));
    return r;
}
static __device__ __forceinline__ float fadd_nc(float a, float b) {
    float r = a + b;
    asm volatile("" : "+v"(r));
    return r;
}

// ---------------------------------------------------------------------------
// Kernel 0: pre-split refs into bf16 hi/lo pair planes, 16B-grouped layout:
// G[(bk*16+cg)*HW + h] = u32x4{pair(c=cg*8+2m, c=cg*8+2m+1), m=0..3}.
// Reads and writes fully coalesced (lane = h).
// ---------------------------------------------------------------------------
__global__ void presplit_kernel(const float* __restrict__ refs,
                                u32x4* __restrict__ Ghi,
                                u32x4* __restrict__ Glo) {
    int i = blockIdx.x * blockDim.x + threadIdx.x;   // over B*K*16*HW
    int h  = i & (HW_ - 1);
    int cg = (i >> 12) & 15;
    int bk = i >> 16;
    const float* p = refs + ((size_t)bk * C_ + cg * 8) * HW_ + h;
    u32x4 H, L;
#pragma unroll
    for (int m = 0; m < 4; ++m) {
        float x = p[(size_t)(2 * m) * HW_];
        float y = p[(size_t)(2 * m + 1) * HW_];
        unsigned hp, lp;
        split2(x, y, hp, lp);
        H[m] = hp; L[m] = lp;
    }
    Ghi[i] = H;
    Glo[i] = L;
}

// ---------------------------------------------------------------------------
// Kernel 1: per-(b,k,h) inverse L2 norm over c (fast fp32 guide values).
// ---------------------------------------------------------------------------
__global__ void norm_kernel(const float* __restrict__ refs,
                            float* __restrict__ inv) {
    int i = blockIdx.x * blockDim.x + threadIdx.x;   // over B*K*HW
    int h  = i & (HW_ - 1);
    int bk = i >> 12;
    const float* p = refs + (size_t)bk * C_ * HW_ + h;
    float ss = 0.f;
#pragma unroll 8
    for (int c = 0; c < C_; ++c) {
        float v = p[(size_t)c * HW_];
        ss = fmaf(v, v, ss);
    }
    inv[i] = 1.0f / fmaxf(sqrtf(ss), 1e-12f);
}

// ---------------------------------------------------------------------------
// Kernel 2: gather query vectors A[b][q][c] = feat[b][c][fi(b,q)].
// ---------------------------------------------------------------------------
__global__ void aprep_kernel(const float* __restrict__ feat,
                             const int* __restrict__ fidx,
                             float* __restrict__ A) {
    int i = blockIdx.x * blockDim.x + threadIdx.x;   // over B*NUM*C
    int c  = i & (C_ - 1);
    int bq = i >> 7;
    int fi = fidx[bq];
    int b  = bq >> 11;
    A[i] = feat[((size_t)b * C_ + c) * HW_ + fi];
}

// ======================== shared GEMM epilogue macro =======================
// 16-lane bitonic merge of per-lane top-2 lists -> top-4 candidates + gap.
#define TOPK_EPILOGUE()                                                       \
  _Pragma("unroll")                                                           \
  for (int rw = 0; rw < 8; ++rw) {                                            \
      float av[4] = {tv1[rw], tv2[rw], -INFINITY, -INFINITY};                 \
      int   ai[4] = {ti1[rw], ti2[rw], 0x7fffffff, 0x7fffffff};               \
      _Pragma("unroll")                                                       \
      for (int s = 1; s <= 8; s <<= 1) {                                      \
          float bv[4]; int bi[4];                                             \
          _Pragma("unroll")                                                   \
          for (int j = 0; j < 4; ++j) {                                       \
              bv[j] = __shfl_xor(av[j], s);                                   \
              bi[j] = __shfl_xor(ai[j], s);                                   \
          }                                                                   \
          float mv[4]; int mi[4];                                             \
          _Pragma("unroll")                                                   \
          for (int j = 0; j < 4; ++j) {                                       \
              bool ta = (av[j] > bv[3-j]) ||                                  \
                        (av[j] == bv[3-j] && ai[j] < bi[3-j]);                \
              mv[j] = ta ? av[j] : bv[3-j];                                   \
              mi[j] = ta ? ai[j] : bi[3-j];                                   \
          }                                                                   \
          CE(0, 2) CE(1, 3) CE(0, 1) CE(2, 3)                                 \
          _Pragma("unroll")                                                   \
          for (int j = 0; j < 4; ++j) { av[j] = mv[j]; ai[j] = mi[j]; }       \
      }                                                                       \
      if (ll == 0) {                                                          \
          int q = qt * 128 + wq * 32 + (rw >> 2) * 16 + lh * 4 + (rw & 3);    \
          size_t o = (size_t)(b * N_ + n) * NUM_ + q;                         \
          cand4[o] = make_int4(ai[0], ai[1], ai[2], ai[3]);                   \
          gaps[o]  = av[0] - av[1];                                           \
      }                                                                       \
  }

#define CE(X,Y) { bool sw_ = (mv[Y] > mv[X]) || (mv[Y] == mv[X] && mi[Y] < mi[X]); \
                  if (sw_) { float tf_ = mv[X]; mv[X] = mv[Y]; mv[Y] = tf_;       \
                             int   td_ = mi[X]; mi[X] = mi[Y]; mi[Y] = td_; } }

// ---------------------------------------------------------------------------
// Kernel 3 (main path): split-bf16 3-pass MFMA GEMM using PRE-SPLIT planes.
// Block: 256 thr (4 waves), tile 128q x 32h, K=128 in A-registers.
// LDS: [buf][plane][32 rows x stride 68 u32] — conflict-minimal b128 r/w.
// ---------------------------------------------------------------------------
__global__ __launch_bounds__(256, 2) void gemm_split_topk_pre(
        const float* __restrict__ A,
        const u32x4* __restrict__ Ghi, const u32x4* __restrict__ Glo,
        const float* __restrict__ inv, const int* __restrict__ pindex,
        int4* __restrict__ cand4, float* __restrict__ gaps) {
    __shared__ unsigned Bsh[2][2][32 * 68];   // 34,816 B

    const int tid = threadIdx.x;
    const int l = tid & 63, wq = tid >> 6;
    const int ll = l & 15, lh = l >> 4;

    // XCD swizzle: 112 consecutive work-ids (7 pairs x 16 q-tiles) per XCD
    int bid = blockIdx.x;
    int swz = (bid & 7) * 112 + (bid >> 3);
    int pair = swz >> 4, qt = swz & 15;
    int b = pair / N_, n = pair % N_;
    int index = pindex[0];
    int ks = n + (n >= index ? 1 : 0);

    const float* Ap   = A   + ((size_t)b * NUM_ + qt * 128 + wq * 32) * C_;
    const u32x4* Gh   = Ghi + (size_t)(b * K_ + ks) * 16 * HW_;
    const u32x4* Gl   = Glo + (size_t)(b * K_ + ks) * 16 * HW_;
    const float* invb = inv + (size_t)(b * K_ + ks) * HW_;

    // ---- A fragments (hi/lo split), persistent in registers ----
    bf16x8 ahi[2][4], alo[2][4];
#pragma unroll
    for (int mf = 0; mf < 2; ++mf)
#pragma unroll
        for (int kk = 0; kk < 4; ++kk) {
            const float* ap = Ap + (mf * 16 + ll) * C_ + kk * 32 + lh * 8;
            float4 xa = *(const float4*)ap;
            float4 xb = *(const float4*)(ap + 4);
            float xs[8] = {xa.x, xa.y, xa.z, xa.w, xb.x, xb.y, xb.z, xb.w};
            u32x4 H, L;
#pragma unroll
            for (int p = 0; p < 4; ++p) {
                unsigned hp, lp;
                split2(xs[2*p], xs[2*p+1], hp, lp);
                H[p] = hp; L[p] = lp;
            }
            ahi[mf][kk] = __builtin_bit_cast(bf16x8, H);
            alo[mf][kk] = __builtin_bit_cast(bf16x8, L);
        }

    // ---- per-lane running top-2 per q-row (8 rows: 2 mf x 4 reg) ----
    float tv1[8], tv2[8]; int ti1[8], ti2[8];
#pragma unroll
    for (int rw = 0; rw < 8; ++rw) {
        tv1[rw] = -INFINITY; tv2[rw] = -INFINITY;
        ti1[rw] = 0; ti2[rw] = 0;
    }

    // ---- staging map: thread -> (row hl, col-group cg8); pure copy ----
    const int hl = tid & 31;          // LDS row / h within tile
    const int cg8 = tid >> 5;         // 0..7
    u32x4 ldr[4];

    // prologue: load tile 0
    ldr[0] = Gh[(size_t)(cg8    ) * HW_ + hl];
    ldr[1] = Gh[(size_t)(cg8 + 8) * HW_ + hl];
    ldr[2] = Gl[(size_t)(cg8    ) * HW_ + hl];
    ldr[3] = Gl[(size_t)(cg8 + 8) * HW_ + hl];

    for (int t = 0; t < 128; ++t) {
        const int cur = t & 1;
        const int ht = t * 32;

        // write tile t into Bsh[cur] (b128, conflict-minimal)
        *(u32x4*)&Bsh[cur][0][hl * 68 + cg8 * 4]       = ldr[0];
        *(u32x4*)&Bsh[cur][0][hl * 68 + (cg8 + 8) * 4] = ldr[1];
        *(u32x4*)&Bsh[cur][1][hl * 68 + cg8 * 4]       = ldr[2];
        *(u32x4*)&Bsh[cur][1][hl * 68 + (cg8 + 8) * 4] = ldr[3];

        // issue loads for tile t+1 (hide under MFMA)
        if (t < 127) {
            int ho = ht + 32 + hl;
            ldr[0] = Gh[(size_t)(cg8    ) * HW_ + ho];
            ldr[1] = Gh[(size_t)(cg8 + 8) * HW_ + ho];
            ldr[2] = Gl[(size_t)(cg8    ) * HW_ + ho];
            ldr[3] = Gl[(size_t)(cg8 + 8) * HW_ + ho];
        }
        __syncthreads();   // tile t visible to all waves

        // ---- 3-pass MFMA: acc = Ah*Bh + Ah*Bl + Al*Bh ----
        f32x4 acc[2][2];
#pragma unroll
        for (int mf = 0; mf < 2; ++mf)
#pragma unroll
            for (int nf = 0; nf < 2; ++nf) acc[mf][nf] = 0.f;

#pragma unroll
        for (int kk = 0; kk < 4; ++kk) {
#pragma unroll
            for (int nf = 0; nf < 2; ++nf) {
                int off = (nf * 16 + ll) * 68 + (kk * 4 + lh) * 4;
                u32x4 bhu = *(const u32x4*)&Bsh[cur][0][off];
                u32x4 blu = *(const u32x4*)&Bsh[cur][1][off];
                bf16x8 bh = __builtin_bit_cast(bf16x8, bhu);
                bf16x8 bl = __builtin_bit_cast(bf16x8, blu);
#pragma unroll
                for (int mf = 0; mf < 2; ++mf) {
                    f32x4 a_ = acc[mf][nf];
                    a_ = mf16(ahi[mf][kk], bh, a_);
                    a_ = mf16(ahi[mf][kk], bl, a_);
                    a_ = mf16(alo[mf][kk], bh, a_);
                    acc[mf][nf] = a_;
                }
            }
        }

        // ---- scale by invnorm, running top-2 (h ascending) ----
        float iv0 = invb[ht + ll];
        float iv1 = invb[ht + 16 + ll];
#pragma unroll
        for (int mf = 0; mf < 2; ++mf)
#pragma unroll
            for (int r = 0; r < 4; ++r) {
                int rw = mf * 4 + r;
#pragma unroll
                for (int nf = 0; nf < 2; ++nf) {
                    float s = acc[mf][nf][r] * (nf ? iv1 : iv0);
                    int h = ht + nf * 16 + ll;
                    if (s > tv1[rw]) {
                        tv2[rw] = tv1[rw]; ti2[rw] = ti1[rw];
                        tv1[rw] = s;       ti1[rw] = h;
                    } else if (s > tv2[rw]) {
                        tv2[rw] = s; ti2[rw] = h;
                    }
                }
            }
    }

    TOPK_EPILOGUE()
}

// ---------------------------------------------------------------------------
// Kernel 3 (fallback, small workspace): round-7 on-the-fly split (verbatim).
// ---------------------------------------------------------------------------
__global__ __launch_bounds__(256, 2) void gemm_split_topk_fly(
        const float* __restrict__ A, const float* __restrict__ refs,
        const float* __restrict__ inv, const int* __restrict__ pindex,
        int4* __restrict__ cand4, float* __restrict__ gaps) {
    __shared__ unsigned Bsh[2][32 * 132];

    const int tid = threadIdx.x;
    const int l = tid & 63, wq = tid >> 6;
    const int ll = l & 15, lh = l >> 4;

    int bid = blockIdx.x;
    int swz = (bid & 7) * 112 + (bid >> 3);
    int pair = swz >> 4, qt = swz & 15;
    int b = pair / N_, n = pair % N_;
    int index = pindex[0];
    int ks = n + (n >= index ? 1 : 0);

    const float* Ap   = A    + ((size_t)b * NUM_ + qt * 128 + wq * 32) * C_;
    const float* Bb   = refs + (size_t)(b * K_ + ks) * C_ * HW_;
    const float* invb = inv  + (size_t)(b * K_ + ks) * HW_;

    bf16x8 ahi[2][4], alo[2][4];
#pragma unroll
    for (int mf = 0; mf < 2; ++mf)
#pragma unroll
        for (int kk = 0; kk < 4; ++kk) {
            const float* ap = Ap + (mf * 16 + ll) * C_ + kk * 32 + lh * 8;
            float4 xa = *(const float4*)ap;
            float4 xb = *(const float4*)(ap + 4);
            float xs[8] = {xa.x, xa.y, xa.z, xa.w, xb.x, xb.y, xb.z, xb.w};
            u32x4 H, L;
#pragma unroll
            for (int p = 0; p < 4; ++p) {
                unsigned hp, lp;
                split2(xs[2*p], xs[2*p+1], hp, lp);
                H[p] = hp; L[p] = lp;
            }
            ahi[mf][kk] = __builtin_bit_cast(bf16x8, H);
            alo[mf][kk] = __builtin_bit_cast(bf16x8, L);
        }

    float tv1[8], tv2[8]; int ti1[8], ti2[8];
#pragma unroll
    for (int rw = 0; rw < 8; ++rw) {
        tv1[rw] = -INFINITY; tv2[rw] = -INFINITY;
        ti1[rw] = 0; ti2[rw] = 0;
    }

    const int hq = tid & 7, h0 = hq * 4;
    const int cp = tid >> 3;
    float4 ldr[4];
#pragma unroll
    for (int i = 0; i < 2; ++i) {
        int c = 2 * cp + 64 * i;
        ldr[2*i]   = *(const float4*)(Bb + (size_t)c * HW_ + h0);
        ldr[2*i+1] = *(const float4*)(Bb + (size_t)(c + 1) * HW_ + h0);
    }

    for (int t = 0; t < 128; ++t) {
        const int cur = t & 1;
        const int ht = t * 32;
#pragma unroll
        for (int i = 0; i < 2; ++i) {
            int c = 2 * cp + 64 * i;
            int g8 = c >> 3;
            int pw = cp & 3;
            float a0[4] = {ldr[2*i].x,   ldr[2*i].y,   ldr[2*i].z,   ldr[2*i].w};
            float a1[4] = {ldr[2*i+1].x, ldr[2*i+1].y, ldr[2*i+1].z, ldr[2*i+1].w};
#pragma unroll
            for (int j = 0; j < 4; ++j) {
                unsigned hp, lp;
                split2(a0[j], a1[j], hp, lp);
                int base = (h0 + j) * 132 + g8 * 8;
                Bsh[cur][base + pw]     = hp;
                Bsh[cur][base + 4 + pw] = lp;
            }
        }
        if (t < 127) {
            int ht1 = ht + 32;
#pragma unroll
            for (int i = 0; i < 2; ++i) {
                int c = 2 * cp + 64 * i;
                ldr[2*i]   = *(const float4*)(Bb + (size_t)c * HW_ + ht1 + h0);
                ldr[2*i+1] = *(const float4*)(Bb + (size_t)(c + 1) * HW_ + ht1 + h0);
            }
        }
        __syncthreads();

        f32x4 acc[2][2];
#pragma unroll
        for (int mf = 0; mf < 2; ++mf)
#pragma unroll
            for (int nf = 0; nf < 2; ++nf) acc[mf][nf] = 0.f;

#pragma unroll
        for (int kk = 0; kk < 4; ++kk) {
#pragma unroll
            for (int nf = 0; nf < 2; ++nf) {
                int base = (nf * 16 + ll) * 132 + (kk * 4 + lh) * 8;
                u32x4 bhu = *(const u32x4*)&Bsh[cur][base];
                u32x4 blu = *(const u32x4*)&Bsh[cur][base + 4];
                bf16x8 bh = __builtin_bit_cast(bf16x8, bhu);
                bf16x8 bl = __builtin_bit_cast(bf16x8, blu);
#pragma unroll
                for (int mf = 0; mf < 2; ++mf) {
                    f32x4 a_ = acc[mf][nf];
                    a_ = mf16(ahi[mf][kk], bh, a_);
                    a_ = mf16(ahi[mf][kk], bl, a_);
                    a_ = mf16(alo[mf][kk], bh, a_);
                    acc[mf][nf] = a_;
                }
            }
        }

        float iv0 = invb[ht + ll];
        float iv1 = invb[ht + 16 + ll];
#pragma unroll
        for (int mf = 0; mf < 2; ++mf)
#pragma unroll
            for (int r = 0; r < 4; ++r) {
                int rw = mf * 4 + r;
#pragma unroll
                for (int nf = 0; nf < 2; ++nf) {
                    float s = acc[mf][nf][r] * (nf ? iv1 : iv0);
                    int h = ht + nf * 16 + ll;
                    if (s > tv1[rw]) {
                        tv2[rw] = tv1[rw]; ti2[rw] = ti1[rw];
                        tv1[rw] = s;       ti1[rw] = h;
                    } else if (s > tv2[rw]) {
                        tv2[rw] = s; ti2[rw] = h;
                    }
                }
            }
    }

    TOPK_EPILOGUE()
}
#undef CE

// ---------------------------------------------------------------------------
// numpy pairwise sum (n=128) — verbatim from the passing round-6 kernel.
// ---------------------------------------------------------------------------
static __device__ float pairwise128_sumsq_div(const float* __restrict__ x,
                                              float d) {
    float r[8];
#pragma unroll
    for (int j = 0; j < 8; ++j) {
        float v = __fdiv_rn(x[j], d);
        r[j] = fmul_nc(v, v);
    }
    for (int i = 8; i < C_; i += 8) {
#pragma unroll
        for (int j = 0; j < 8; ++j) {
            float v = __fdiv_rn(x[i + j], d);
            r[j] = fadd_nc(r[j], fmul_nc(v, v));
        }
    }
    return fadd_nc(fadd_nc(fadd_nc(r[0], r[1]), fadd_nc(r[2], r[3])),
                   fadd_nc(fadd_nc(r[4], r[5]), fadd_nc(r[6], r[7])));
}

// Emulated numpy score (verbatim from round 6 — all non-FMA where numpy is).
static __device__ float emul_score(const float* __restrict__ qp,
                                   const float* __restrict__ Rb,
                                   int h, float n1, float n2) {
    float rv0 = Rb[h];
    float sr = fmul_nc(rv0, rv0);
    for (int c = 1; c < C_; ++c) {
        float rv = Rb[(size_t)c * HW_ + h];
        sr = fadd_nc(sr, fmul_nc(rv, rv));
    }
    float nr = fmaxf(__fsqrt_rn(sr), 1e-12f);
    float acc = 0.f;
    for (int c = 0; c < C_; ++c) {
        float w2 = __fdiv_rn(__fdiv_rn(qp[c], n1), n2);
        float wr = __fdiv_rn(Rb[(size_t)c * HW_ + h], nr);
        acc = fadd_nc(acc, fmul_nc(w2, wr));
    }
    return acc;
}

// ---------------------------------------------------------------------------
// Kernel 3b: adjudicate split-GEMM top-4. Prune when split gap is decisive;
// else exact numpy emulation of all 4 candidates, lowest-index tie-break.
// ---------------------------------------------------------------------------
__global__ void rescore_emul4(const float* __restrict__ A,
                              const float* __restrict__ refs,
                              const int* __restrict__ pindex,
                              const int4* __restrict__ cand4,
                              const float* __restrict__ gaps,
                              int* __restrict__ idxout,
                              float* __restrict__ out2) {
    int r = blockIdx.x * blockDim.x + threadIdx.x;   // over B*N*NUM
    if (r >= B_ * N_ * NUM_) return;
    int4 cd = cand4[r];
    int win;
    if (gaps[r] > 5e-5f) {
        win = cd.x;
    } else {
        int q  = r & (NUM_ - 1);
        int bn = r >> 11;
        int b = bn / N_, n = bn % N_;
        int index = pindex[0];
        int ks = n + (n >= index ? 1 : 0);
        const float* qp = A    + ((size_t)b * NUM_ + q) * C_;
        const float* Rb = refs + (size_t)(b * K_ + ks) * C_ * HW_;
        float s1 = pairwise128_sumsq_div(qp, 1.0f);
        float n1 = fmaxf(__fsqrt_rn(s1), 1e-12f);
        float s2 = pairwise128_sumsq_div(qp, n1);
        float n2 = fmaxf(__fsqrt_rn(s2), 1e-12f);
        float sa = emul_score(qp, Rb, cd.x, n1, n2);
        float sb = emul_score(qp, Rb, cd.y, n1, n2);
        float sc = emul_score(qp, Rb, cd.z, n1, n2);
        float sd = emul_score(qp, Rb, cd.w, n1, n2);
        win = cd.x; float bw = sa;
        if (sb > bw || (sb == bw && cd.y < win)) { bw = sb; win = cd.y; }
        if (sc > bw || (sc == bw && cd.z < win)) { bw = sc; win = cd.z; }
        if (sd > bw || (sd == bw && cd.w < win)) { bw = sd; win = cd.w; }
    }
    idxout[r] = win;
    out2[r]   = (float)win;
}

// ---------------------------------------------------------------------------
// Kernel 4: fused = base_sim*feat_sel + sum_n sims[n]*refs[b,kn,:,idx_n],
// scattered into out[b][c][fi]. Also writes feat_indices output as float.
// ---------------------------------------------------------------------------
__global__ void fuse_scatter(const float* __restrict__ A,
                             const float* __restrict__ refs,
                             const float* __restrict__ sim,
                             const int* __restrict__ fidx,
                             const int* __restrict__ pindex,
                             const int* __restrict__ idxbuf,
                             float* __restrict__ out0,
                             float* __restrict__ out1) {
    int bq = blockIdx.x;                 // over B*NUM
    int q  = bq & (NUM_ - 1);
    int b  = bq >> 11;
    int c  = threadIdx.x;                // 128 threads
    int index = pindex[0];
    int fi = fidx[bq];

    float v = sim[b * K_ + index] * A[(size_t)bq * C_ + c];
#pragma unroll
    for (int n = 0; n < N_; ++n) {
        int ks = n + (n >= index ? 1 : 0);
        int id = idxbuf[(size_t)(b * N_ + n) * NUM_ + q];
        v = fmaf(sim[b * K_ + ks],
                 refs[((size_t)(b * K_ + ks) * C_ + c) * HW_ + id], v);
    }
    out0[((size_t)b * C_ + c) * HW_ + fi] = v;
    if (c == 0) out1[bq] = (float)fi;
}

// ---------------------------------------------------------------------------
extern "C" void kernel_launch(void* const* d_in, const int* in_sizes, int n_in,
                              void* d_out, int out_size, void* d_ws, size_t ws_size,
                              hipStream_t stream) {
    const float* feat = (const float*)d_in[0];   // [B][C][HW]
    const float* refs = (const float*)d_in[1];   // [B][K][C][HW]
    const float* sim  = (const float*)d_in[2];   // [B][K]
    const int*   fidx = (const int*)d_in[3];     // [B][NUM]
    const int*   pidx = (const int*)d_in[4];     // scalar index

    float* wsf   = (float*)d_ws;
    float* A     = wsf + WS_A_OFF;
    float* inv   = wsf + WS_INV_OFF;
    int4*  cand  = (int4*)(wsf + WS_CAND_OFF);
    float* gaps  = wsf + WS_GAP_OFF;
    int*   idxf  = (int*)(wsf + WS_IDX_OFF);
    u32x4* Ghi   = (u32x4*)(wsf + WS_GHI_OFF);
    u32x4* Glo   = Ghi + GPLANE_V4;

    float* out0 = (float*)d_out;                       // [B][C][HW]
    float* out1 = out0 + (size_t)B_ * C_ * HW_;        // feat_indices (f32)
    float* out2 = out1 + (size_t)B_ * NUM_;            // ref_indices (f32)

    // does the workspace fit the pre-split planes (ws_size is fixed per run,
    // so this branch is deterministic and graph-capture-safe)?
    const size_t need = ((size_t)WS_GHI_OFF + 2ull * GPLANE_V4 * 4) * 4;
    const bool big = ws_size >= need;

    norm_kernel<<<(B_ * K_ * HW_) / 256, 256, 0, stream>>>(refs, inv);
    aprep_kernel<<<(B_ * NUM_ * C_) / 256, 256, 0, stream>>>(feat, fidx, A);
    hipMemcpyAsync(out0, feat, (size_t)B_ * C_ * HW_ * sizeof(float),
                   hipMemcpyDeviceToDevice, stream);
    if (big) {
        presplit_kernel<<<(B_ * K_ * 16 * HW_) / 256, 256, 0, stream>>>(
            refs, Ghi, Glo);
        gemm_split_topk_pre<<<56 * 16, 256, 0, stream>>>(A, Ghi, Glo, inv,
                                                         pidx, cand, gaps);
    } else {
        gemm_split_topk_fly<<<56 * 16, 256, 0, stream>>>(A, refs, inv, pidx,
                                                         cand, gaps);
    }
    rescore_emul4<<<(B_ * N_ * NUM_ + 255) / 256, 256, 0, stream>>>(
        A, refs, pidx, cand, gaps, idxf, out2);
    fuse_scatter<<<B_ * NUM_, 128, 0, stream>>>(A, refs, sim, fidx, pidx,
                                                idxf, out0, out1);
}

// Round 9
// 1397.816 us; speedup vs baseline: 2.3189x; 1.0131x over previous
//
#include <hip/hip_runtime.h>
#include <math.h>

#define B_    8
#define K_    8
#define C_    128
#define HW_   4096
#define NUM_  2048
#define N_    7          // K-1 refs used

// ---------------- workspace layout (32-bit words) ----------------
#define WS_A_OFF    0                               // [B][NUM][C] floats
#define WS_INV_OFF  (B_*NUM_*C_)                    // [B][K][HW] floats
#define WS_CAND_OFF (WS_INV_OFF + B_*K_*HW_)        // [B][N][NUM] int4
#define WS_GAP_OFF  (WS_CAND_OFF + B_*N_*NUM_*4)    // [B][N][NUM] float
#define WS_IDX_OFF  (WS_GAP_OFF + B_*N_*NUM_)       // [B][N][NUM] int
#define WS_GHI_OFF  (WS_IDX_OFF + B_*N_*NUM_)       // pre-split planes
#define GPLANE_V4   (B_*K_*16*HW_)                  // u32x4 per plane

typedef __bf16 bf16x8 __attribute__((ext_vector_type(8)));
typedef float  f32x4  __attribute__((ext_vector_type(4)));
typedef unsigned int u32x4 __attribute__((ext_vector_type(4)));

static __device__ __forceinline__ f32x4 mf16(bf16x8 a, bf16x8 b, f32x4 c) {
    return __builtin_amdgcn_mfma_f32_16x16x32_bf16(a, b, c, 0, 0, 0);
}

// RTNE bf16 high-part (bit math, branch-free)
static __device__ __forceinline__ unsigned bfhi16(float x) {
    unsigned b = __float_as_uint(x);
    return (b + 0x7fffu + ((b >> 16) & 1u)) >> 16;
}
// split two floats (consecutive c) into packed hi-pair and lo-pair u32
static __device__ __forceinline__ void split2(float x, float y,
                                              unsigned &hp, unsigned &lp) {
    unsigned hx = bfhi16(x), hy = bfhi16(y);
    float rx = x - __uint_as_float(hx << 16);
    float ry = y - __uint_as_float(hy << 16);
    hp = hx | (hy << 16);
    lp = bfhi16(rx) | (bfhi16(ry) << 16);
}

// ---- contraction-proof mul/add (verbatim from the passing round-6 kernel)
static __device__ __forceinline__ float fmul_nc(float a, float b) {
    float r = a * b;
    asm volatile("" : "+v"(r));
    return r;
}
static __device__ __forceinline__ float fadd_nc(float a, float b) {
    float r = a + b;
    asm volatile("" : "+v"(r));
    return r;
}

// ---------------------------------------------------------------------------
// Kernel 0: pre-split refs into bf16 hi/lo pair planes, 16B-grouped layout:
// G[(bk*16+cg)*HW + h] = u32x4{pair(c=cg*8+2m, c=cg*8+2m+1), m=0..3}.
// ---------------------------------------------------------------------------
__global__ void presplit_kernel(const float* __restrict__ refs,
                                u32x4* __restrict__ Ghi,
                                u32x4* __restrict__ Glo) {
    int i = blockIdx.x * blockDim.x + threadIdx.x;   // over B*K*16*HW
    int h  = i & (HW_ - 1);
    int cg = (i >> 12) & 15;
    int bk = i >> 16;
    const float* p = refs + ((size_t)bk * C_ + cg * 8) * HW_ + h;
    u32x4 H, L;
#pragma unroll
    for (int m = 0; m < 4; ++m) {
        float x = p[(size_t)(2 * m) * HW_];
        float y = p[(size_t)(2 * m + 1) * HW_];
        unsigned hp, lp;
        split2(x, y, hp, lp);
        H[m] = hp; L[m] = lp;
    }
    Ghi[i] = H;
    Glo[i] = L;
}

// ---------------------------------------------------------------------------
// Kernel 1: per-(b,k,h) inverse L2 norm over c (fast fp32 guide values).
// ---------------------------------------------------------------------------
__global__ void norm_kernel(const float* __restrict__ refs,
                            float* __restrict__ inv) {
    int i = blockIdx.x * blockDim.x + threadIdx.x;   // over B*K*HW
    int h  = i & (HW_ - 1);
    int bk = i >> 12;
    const float* p = refs + (size_t)bk * C_ * HW_ + h;
    float ss = 0.f;
#pragma unroll 8
    for (int c = 0; c < C_; ++c) {
        float v = p[(size_t)c * HW_];
        ss = fmaf(v, v, ss);
    }
    inv[i] = 1.0f / fmaxf(sqrtf(ss), 1e-12f);
}

// ---------------------------------------------------------------------------
// Kernel 2: gather query vectors A[b][q][c] = feat[b][c][fi(b,q)].
// ---------------------------------------------------------------------------
__global__ void aprep_kernel(const float* __restrict__ feat,
                             const int* __restrict__ fidx,
                             float* __restrict__ A) {
    int i = blockIdx.x * blockDim.x + threadIdx.x;   // over B*NUM*C
    int c  = i & (C_ - 1);
    int bq = i >> 7;
    int fi = fidx[bq];
    int b  = bq >> 11;
    A[i] = feat[((size_t)b * C_ + c) * HW_ + fi];
}

// ======================== shared GEMM epilogue macro =======================
#define TOPK_EPILOGUE()                                                       \
  _Pragma("unroll")                                                           \
  for (int rw = 0; rw < 8; ++rw) {                                            \
      float av[4] = {tv1[rw], tv2[rw], -INFINITY, -INFINITY};                 \
      int   ai[4] = {ti1[rw], ti2[rw], 0x7fffffff, 0x7fffffff};               \
      _Pragma("unroll")                                                       \
      for (int s = 1; s <= 8; s <<= 1) {                                      \
          float bv[4]; int bi[4];                                             \
          _Pragma("unroll")                                                   \
          for (int j = 0; j < 4; ++j) {                                       \
              bv[j] = __shfl_xor(av[j], s);                                   \
              bi[j] = __shfl_xor(ai[j], s);                                   \
          }                                                                   \
          float mv[4]; int mi[4];                                             \
          _Pragma("unroll")                                                   \
          for (int j = 0; j < 4; ++j) {                                       \
              bool ta = (av[j] > bv[3-j]) ||                                  \
                        (av[j] == bv[3-j] && ai[j] < bi[3-j]);                \
              mv[j] = ta ? av[j] : bv[3-j];                                   \
              mi[j] = ta ? ai[j] : bi[3-j];                                   \
          }                                                                   \
          CE(0, 2) CE(1, 3) CE(0, 1) CE(2, 3)                                 \
          _Pragma("unroll")                                                   \
          for (int j = 0; j < 4; ++j) { av[j] = mv[j]; ai[j] = mi[j]; }       \
      }                                                                       \
      if (ll == 0) {                                                          \
          int q = qt * 128 + wq * 32 + (rw >> 2) * 16 + lh * 4 + (rw & 3);    \
          size_t o = (size_t)(b * N_ + n) * NUM_ + q;                         \
          cand4[o] = make_int4(ai[0], ai[1], ai[2], ai[3]);                   \
          gaps[o]  = av[0] - av[1];                                           \
      }                                                                       \
  }

#define CE(X,Y) { bool sw_ = (mv[Y] > mv[X]) || (mv[Y] == mv[X] && mi[Y] < mi[X]); \
                  if (sw_) { float tf_ = mv[X]; mv[X] = mv[Y]; mv[Y] = tf_;       \
                             int   td_ = mi[X]; mi[X] = mi[Y]; mi[Y] = td_; } }

// ---------------------------------------------------------------------------
// Kernel 3 (main): split-bf16 3-pass MFMA GEMM, PRE-SPLIT planes, PIPELINED:
//   per iter: [ds_write(t) | barrier | ISSUE loads(t+1) | MFMA+top2(t)]
// so global loads age across the whole compute phase before any drain.
// LDS: [2 buf][2 plane][16 cg][32 h] u32x4, linear (conflict-free b128 r/w).
// ---------------------------------------------------------------------------
__global__ __launch_bounds__(256, 3) void gemm_split_topk_pipe(
        const float* __restrict__ A,
        const u32x4* __restrict__ Ghi, const u32x4* __restrict__ Glo,
        const float* __restrict__ inv, const int* __restrict__ pindex,
        int4* __restrict__ cand4, float* __restrict__ gaps) {
    __shared__ u32x4 Bsh[2][2][512];   // 32 KiB

    const int tid = threadIdx.x;
    const int l = tid & 63, wq = tid >> 6;
    const int ll = l & 15, lh = l >> 4;

    // XCD swizzle: 112 consecutive work-ids (7 pairs x 16 q-tiles) per XCD
    int bid = blockIdx.x;
    int swz = (bid & 7) * 112 + (bid >> 3);
    int pair = swz >> 4, qt = swz & 15;
    int b = pair / N_, n = pair % N_;
    int index = pindex[0];
    int ks = n + (n >= index ? 1 : 0);

    const float* Ap   = A   + ((size_t)b * NUM_ + qt * 128 + wq * 32) * C_;
    const u32x4* Gh   = Ghi + (size_t)(b * K_ + ks) * 16 * HW_;
    const u32x4* Gl   = Glo + (size_t)(b * K_ + ks) * 16 * HW_;
    const float* invb = inv + (size_t)(b * K_ + ks) * HW_;

    // ---- A fragments (hi/lo split), persistent in registers ----
    bf16x8 ahi[2][4], alo[2][4];
#pragma unroll
    for (int mf = 0; mf < 2; ++mf)
#pragma unroll
        for (int kk = 0; kk < 4; ++kk) {
            const float* ap = Ap + (mf * 16 + ll) * C_ + kk * 32 + lh * 8;
            float4 xa = *(const float4*)ap;
            float4 xb = *(const float4*)(ap + 4);
            float xs[8] = {xa.x, xa.y, xa.z, xa.w, xb.x, xb.y, xb.z, xb.w};
            u32x4 H, L;
#pragma unroll
            for (int p = 0; p < 4; ++p) {
                unsigned hp, lp;
                split2(xs[2*p], xs[2*p+1], hp, lp);
                H[p] = hp; L[p] = lp;
            }
            ahi[mf][kk] = __builtin_bit_cast(bf16x8, H);
            alo[mf][kk] = __builtin_bit_cast(bf16x8, L);
        }

    // ---- per-lane running top-2 per q-row (8 rows: 2 mf x 4 reg) ----
    float tv1[8], tv2[8]; int ti1[8], ti2[8];
#pragma unroll
    for (int rw = 0; rw < 8; ++rw) {
        tv1[rw] = -INFINITY; tv2[rw] = -INFINITY;
        ti1[rw] = 0; ti2[rw] = 0;
    }

    // ---- staging map: thread stages u32x4 idx {tid, tid+256} per plane ----
    const int scg0 = tid >> 5;        // 0..7
    const int scg1 = scg0 + 8;        // 8..15
    const int sh   = tid & 31;        // h within tile

    // prologue: load tile 0 into regs
    u32x4 rh0 = Gh[(size_t)scg0 * HW_ + sh];
    u32x4 rh1 = Gh[(size_t)scg1 * HW_ + sh];
    u32x4 rl0 = Gl[(size_t)scg0 * HW_ + sh];
    u32x4 rl1 = Gl[(size_t)scg1 * HW_ + sh];
    float civ0 = invb[ll], civ1 = invb[16 + ll];

    for (int t = 0; t < 128; ++t) {
        const int cur = t & 1;
        const int ht = t * 32;

        // 1) write tile t into LDS (vm-wait here sees loads aged a full iter)
        Bsh[cur][0][tid]       = rh0;
        Bsh[cur][0][tid + 256] = rh1;
        Bsh[cur][1][tid]       = rl0;
        Bsh[cur][1][tid + 256] = rl1;
        __syncthreads();   // 2) barrier BEFORE issuing next loads

        // 3) issue tile t+1 loads — they age across the MFMA phase below
        float niv0, niv1;
        if (t < 127) {
            int o = ht + 32 + sh;
            rh0 = Gh[(size_t)scg0 * HW_ + o];
            rh1 = Gh[(size_t)scg1 * HW_ + o];
            rl0 = Gl[(size_t)scg0 * HW_ + o];
            rl1 = Gl[(size_t)scg1 * HW_ + o];
            niv0 = invb[ht + 32 + ll];
            niv1 = invb[ht + 48 + ll];
        }

        // 4) 3-pass MFMA: acc = Ah*Bh + Ah*Bl + Al*Bh
        f32x4 acc[2][2];
#pragma unroll
        for (int mf = 0; mf < 2; ++mf)
#pragma unroll
            for (int nf = 0; nf < 2; ++nf) acc[mf][nf] = 0.f;

#pragma unroll
        for (int kk = 0; kk < 4; ++kk) {
#pragma unroll
            for (int nf = 0; nf < 2; ++nf) {
                int off = (kk * 4 + lh) * 32 + nf * 16 + ll;
                u32x4 bhu = Bsh[cur][0][off];
                u32x4 blu = Bsh[cur][1][off];
                bf16x8 bh = __builtin_bit_cast(bf16x8, bhu);
                bf16x8 bl = __builtin_bit_cast(bf16x8, blu);
#pragma unroll
                for (int mf = 0; mf < 2; ++mf) {
                    f32x4 a_ = acc[mf][nf];
                    a_ = mf16(ahi[mf][kk], bh, a_);
                    a_ = mf16(ahi[mf][kk], bl, a_);
                    a_ = mf16(alo[mf][kk], bh, a_);
                    acc[mf][nf] = a_;
                }
            }
        }

        // 5) scale by invnorm, running top-2 (h ascending)
#pragma unroll
        for (int mf = 0; mf < 2; ++mf)
#pragma unroll
            for (int r = 0; r < 4; ++r) {
                int rw = mf * 4 + r;
#pragma unroll
                for (int nf = 0; nf < 2; ++nf) {
                    float s = acc[mf][nf][r] * (nf ? civ1 : civ0);
                    int h = ht + nf * 16 + ll;
                    if (s > tv1[rw]) {
                        tv2[rw] = tv1[rw]; ti2[rw] = ti1[rw];
                        tv1[rw] = s;       ti1[rw] = h;
                    } else if (s > tv2[rw]) {
                        tv2[rw] = s; ti2[rw] = h;
                    }
                }
            }
        if (t < 127) { civ0 = niv0; civ1 = niv1; }
    }

    TOPK_EPILOGUE()
}

// ---------------------------------------------------------------------------
// Kernel 3 (fallback, small workspace): round-7 on-the-fly split (verbatim).
// ---------------------------------------------------------------------------
__global__ __launch_bounds__(256, 2) void gemm_split_topk_fly(
        const float* __restrict__ A, const float* __restrict__ refs,
        const float* __restrict__ inv, const int* __restrict__ pindex,
        int4* __restrict__ cand4, float* __restrict__ gaps) {
    __shared__ unsigned Bsh[2][32 * 132];

    const int tid = threadIdx.x;
    const int l = tid & 63, wq = tid >> 6;
    const int ll = l & 15, lh = l >> 4;

    int bid = blockIdx.x;
    int swz = (bid & 7) * 112 + (bid >> 3);
    int pair = swz >> 4, qt = swz & 15;
    int b = pair / N_, n = pair % N_;
    int index = pindex[0];
    int ks = n + (n >= index ? 1 : 0);

    const float* Ap   = A    + ((size_t)b * NUM_ + qt * 128 + wq * 32) * C_;
    const float* Bb   = refs + (size_t)(b * K_ + ks) * C_ * HW_;
    const float* invb = inv  + (size_t)(b * K_ + ks) * HW_;

    bf16x8 ahi[2][4], alo[2][4];
#pragma unroll
    for (int mf = 0; mf < 2; ++mf)
#pragma unroll
        for (int kk = 0; kk < 4; ++kk) {
            const float* ap = Ap + (mf * 16 + ll) * C_ + kk * 32 + lh * 8;
            float4 xa = *(const float4*)ap;
            float4 xb = *(const float4*)(ap + 4);
            float xs[8] = {xa.x, xa.y, xa.z, xa.w, xb.x, xb.y, xb.z, xb.w};
            u32x4 H, L;
#pragma unroll
            for (int p = 0; p < 4; ++p) {
                unsigned hp, lp;
                split2(xs[2*p], xs[2*p+1], hp, lp);
                H[p] = hp; L[p] = lp;
            }
            ahi[mf][kk] = __builtin_bit_cast(bf16x8, H);
            alo[mf][kk] = __builtin_bit_cast(bf16x8, L);
        }

    float tv1[8], tv2[8]; int ti1[8], ti2[8];
#pragma unroll
    for (int rw = 0; rw < 8; ++rw) {
        tv1[rw] = -INFINITY; tv2[rw] = -INFINITY;
        ti1[rw] = 0; ti2[rw] = 0;
    }

    const int hq = tid & 7, h0 = hq * 4;
    const int cp = tid >> 3;
    float4 ldr[4];
#pragma unroll
    for (int i = 0; i < 2; ++i) {
        int c = 2 * cp + 64 * i;
        ldr[2*i]   = *(const float4*)(Bb + (size_t)c * HW_ + h0);
        ldr[2*i+1] = *(const float4*)(Bb + (size_t)(c + 1) * HW_ + h0);
    }

    for (int t = 0; t < 128; ++t) {
        const int cur = t & 1;
        const int ht = t * 32;
#pragma unroll
        for (int i = 0; i < 2; ++i) {
            int c = 2 * cp + 64 * i;
            int g8 = c >> 3;
            int pw = cp & 3;
            float a0[4] = {ldr[2*i].x,   ldr[2*i].y,   ldr[2*i].z,   ldr[2*i].w};
            float a1[4] = {ldr[2*i+1].x, ldr[2*i+1].y, ldr[2*i+1].z, ldr[2*i+1].w};
#pragma unroll
            for (int j = 0; j < 4; ++j) {
                unsigned hp, lp;
                split2(a0[j], a1[j], hp, lp);
                int base = (h0 + j) * 132 + g8 * 8;
                Bsh[cur][base + pw]     = hp;
                Bsh[cur][base + 4 + pw] = lp;
            }
        }
        if (t < 127) {
            int ht1 = ht + 32;
#pragma unroll
            for (int i = 0; i < 2; ++i) {
                int c = 2 * cp + 64 * i;
                ldr[2*i]   = *(const float4*)(Bb + (size_t)c * HW_ + ht1 + h0);
                ldr[2*i+1] = *(const float4*)(Bb + (size_t)(c + 1) * HW_ + ht1 + h0);
            }
        }
        __syncthreads();

        f32x4 acc[2][2];
#pragma unroll
        for (int mf = 0; mf < 2; ++mf)
#pragma unroll
            for (int nf = 0; nf < 2; ++nf) acc[mf][nf] = 0.f;

#pragma unroll
        for (int kk = 0; kk < 4; ++kk) {
#pragma unroll
            for (int nf = 0; nf < 2; ++nf) {
                int base = (nf * 16 + ll) * 132 + (kk * 4 + lh) * 8;
                u32x4 bhu = *(const u32x4*)&Bsh[cur][base];
                u32x4 blu = *(const u32x4*)&Bsh[cur][base + 4];
                bf16x8 bh = __builtin_bit_cast(bf16x8, bhu);
                bf16x8 bl = __builtin_bit_cast(bf16x8, blu);
#pragma unroll
                for (int mf = 0; mf < 2; ++mf) {
                    f32x4 a_ = acc[mf][nf];
                    a_ = mf16(ahi[mf][kk], bh, a_);
                    a_ = mf16(ahi[mf][kk], bl, a_);
                    a_ = mf16(alo[mf][kk], bh, a_);
                    acc[mf][nf] = a_;
                }
            }
        }

        float iv0 = invb[ht + ll];
        float iv1 = invb[ht + 16 + ll];
#pragma unroll
        for (int mf = 0; mf < 2; ++mf)
#pragma unroll
            for (int r = 0; r < 4; ++r) {
                int rw = mf * 4 + r;
#pragma unroll
                for (int nf = 0; nf < 2; ++nf) {
                    float s = acc[mf][nf][r] * (nf ? iv1 : iv0);
                    int h = ht + nf * 16 + ll;
                    if (s > tv1[rw]) {
                        tv2[rw] = tv1[rw]; ti2[rw] = ti1[rw];
                        tv1[rw] = s;       ti1[rw] = h;
                    } else if (s > tv2[rw]) {
                        tv2[rw] = s; ti2[rw] = h;
                    }
                }
            }
    }

    TOPK_EPILOGUE()
}
#undef CE

// ---------------------------------------------------------------------------
// numpy pairwise sum (n=128) — verbatim from the passing round-6 kernel.
// ---------------------------------------------------------------------------
static __device__ float pairwise128_sumsq_div(const float* __restrict__ x,
                                              float d) {
    float r[8];
#pragma unroll
    for (int j = 0; j < 8; ++j) {
        float v = __fdiv_rn(x[j], d);
        r[j] = fmul_nc(v, v);
    }
    for (int i = 8; i < C_; i += 8) {
#pragma unroll
        for (int j = 0; j < 8; ++j) {
            float v = __fdiv_rn(x[i + j], d);
            r[j] = fadd_nc(r[j], fmul_nc(v, v));
        }
    }
    return fadd_nc(fadd_nc(fadd_nc(r[0], r[1]), fadd_nc(r[2], r[3])),
                   fadd_nc(fadd_nc(r[4], r[5]), fadd_nc(r[6], r[7])));
}

// Emulated numpy score (verbatim from round 6 — all non-FMA where numpy is).
static __device__ float emul_score(const float* __restrict__ qp,
                                   const float* __restrict__ Rb,
                                   int h, float n1, float n2) {
    float rv0 = Rb[h];
    float sr = fmul_nc(rv0, rv0);
    for (int c = 1; c < C_; ++c) {
        float rv = Rb[(size_t)c * HW_ + h];
        sr = fadd_nc(sr, fmul_nc(rv, rv));
    }
    float nr = fmaxf(__fsqrt_rn(sr), 1e-12f);
    float acc = 0.f;
    for (int c = 0; c < C_; ++c) {
        float w2 = __fdiv_rn(__fdiv_rn(qp[c], n1), n2);
        float wr = __fdiv_rn(Rb[(size_t)c * HW_ + h], nr);
        acc = fadd_nc(acc, fmul_nc(w2, wr));
    }
    return acc;
}

// ---------------------------------------------------------------------------
// Kernel 3b: adjudicate split-GEMM top-4. Prune when split gap is decisive;
// else exact numpy emulation of all 4 candidates, lowest-index tie-break.
// ---------------------------------------------------------------------------
__global__ void rescore_emul4(const float* __restrict__ A,
                              const float* __restrict__ refs,
                              const int* __restrict__ pindex,
                              const int4* __restrict__ cand4,
                              const float* __restrict__ gaps,
                              int* __restrict__ idxout,
                              float* __restrict__ out2) {
    int r = blockIdx.x * blockDim.x + threadIdx.x;   // over B*N*NUM
    if (r >= B_ * N_ * NUM_) return;
    int4 cd = cand4[r];
    int win;
    if (gaps[r] > 5e-5f) {
        win = cd.x;
    } else {
        int q  = r & (NUM_ - 1);
        int bn = r >> 11;
        int b = bn / N_, n = bn % N_;
        int index = pindex[0];
        int ks = n + (n >= index ? 1 : 0);
        const float* qp = A    + ((size_t)b * NUM_ + q) * C_;
        const float* Rb = refs + (size_t)(b * K_ + ks) * C_ * HW_;
        float s1 = pairwise128_sumsq_div(qp, 1.0f);
        float n1 = fmaxf(__fsqrt_rn(s1), 1e-12f);
        float s2 = pairwise128_sumsq_div(qp, n1);
        float n2 = fmaxf(__fsqrt_rn(s2), 1e-12f);
        float sa = emul_score(qp, Rb, cd.x, n1, n2);
        float sb = emul_score(qp, Rb, cd.y, n1, n2);
        float sc = emul_score(qp, Rb, cd.z, n1, n2);
        float sd = emul_score(qp, Rb, cd.w, n1, n2);
        win = cd.x; float bw = sa;
        if (sb > bw || (sb == bw && cd.y < win)) { bw = sb; win = cd.y; }
        if (sc > bw || (sc == bw && cd.z < win)) { bw = sc; win = cd.z; }
        if (sd > bw || (sd == bw && cd.w < win)) { bw = sd; win = cd.w; }
    }
    idxout[r] = win;
    out2[r]   = (float)win;
}

// ---------------------------------------------------------------------------
// Kernel 4: fused = base_sim*feat_sel + sum_n sims[n]*refs[b,kn,:,idx_n],
// scattered into out[b][c][fi]. Also writes feat_indices output as float.
// ---------------------------------------------------------------------------
__global__ void fuse_scatter(const float* __restrict__ A,
                             const float* __restrict__ refs,
                             const float* __restrict__ sim,
                             const int* __restrict__ fidx,
                             const int* __restrict__ pindex,
                             const int* __restrict__ idxbuf,
                             float* __restrict__ out0,
                             float* __restrict__ out1) {
    int bq = blockIdx.x;                 // over B*NUM
    int q  = bq & (NUM_ - 1);
    int b  = bq >> 11;
    int c  = threadIdx.x;                // 128 threads
    int index = pindex[0];
    int fi = fidx[bq];

    float v = sim[b * K_ + index] * A[(size_t)bq * C_ + c];
#pragma unroll
    for (int n = 0; n < N_; ++n) {
        int ks = n + (n >= index ? 1 : 0);
        int id = idxbuf[(size_t)(b * N_ + n) * NUM_ + q];
        v = fmaf(sim[b * K_ + ks],
                 refs[((size_t)(b * K_ + ks) * C_ + c) * HW_ + id], v);
    }
    out0[((size_t)b * C_ + c) * HW_ + fi] = v;
    if (c == 0) out1[bq] = (float)fi;
}

// ---------------------------------------------------------------------------
extern "C" void kernel_launch(void* const* d_in, const int* in_sizes, int n_in,
                              void* d_out, int out_size, void* d_ws, size_t ws_size,
                              hipStream_t stream) {
    const float* feat = (const float*)d_in[0];   // [B][C][HW]
    const float* refs = (const float*)d_in[1];   // [B][K][C][HW]
    const float* sim  = (const float*)d_in[2];   // [B][K]
    const int*   fidx = (const int*)d_in[3];     // [B][NUM]
    const int*   pidx = (const int*)d_in[4];     // scalar index

    float* wsf   = (float*)d_ws;
    float* A     = wsf + WS_A_OFF;
    float* inv   = wsf + WS_INV_OFF;
    int4*  cand  = (int4*)(wsf + WS_CAND_OFF);
    float* gaps  = wsf + WS_GAP_OFF;
    int*   idxf  = (int*)(wsf + WS_IDX_OFF);
    u32x4* Ghi   = (u32x4*)(wsf + WS_GHI_OFF);
    u32x4* Glo   = Ghi + GPLANE_V4;

    float* out0 = (float*)d_out;                       // [B][C][HW]
    float* out1 = out0 + (size_t)B_ * C_ * HW_;        // feat_indices (f32)
    float* out2 = out1 + (size_t)B_ * NUM_;            // ref_indices (f32)

    const size_t need = ((size_t)WS_GHI_OFF + 2ull * GPLANE_V4 * 4) * 4;
    const bool big = ws_size >= need;

    norm_kernel<<<(B_ * K_ * HW_) / 256, 256, 0, stream>>>(refs, inv);
    aprep_kernel<<<(B_ * NUM_ * C_) / 256, 256, 0, stream>>>(feat, fidx, A);
    hipMemcpyAsync(out0, feat, (size_t)B_ * C_ * HW_ * sizeof(float),
                   hipMemcpyDeviceToDevice, stream);
    if (big) {
        presplit_kernel<<<(B_ * K_ * 16 * HW_) / 256, 256, 0, stream>>>(
            refs, Ghi, Glo);
        gemm_split_topk_pipe<<<56 * 16, 256, 0, stream>>>(A, Ghi, Glo, inv,
                                                          pidx, cand, gaps);
    } else {
        gemm_split_topk_fly<<<56 * 16, 256, 0, stream>>>(A, refs, inv, pidx,
                                                         cand, gaps);
    }
    rescore_emul4<<<(B_ * N_ * NUM_ + 255) / 256, 256, 0, stream>>>(
        A, refs, pidx, cand, gaps, idxf, out2);
    fuse_scatter<<<B_ * NUM_, 128, 0, stream>>>(A, refs, sim, fidx, pidx,
                                                idxf, out0, out1);
}

// Round 10
// 949.891 us; speedup vs baseline: 3.4124x; 1.4716x over previous
//
#include <hip/hip_runtime.h>
#include <math.h>

#define B_    8
#define K_    8
#define C_    128
#define HW_   4096
#define NUM_  2048
#define N_    7          // K-1 refs used

// ---------------- workspace layout (32-bit words) ----------------
#define WS_A_OFF    0                               // [B][NUM][C] raw q
#define WS_INV_OFF  (B_*NUM_*C_)                    // [B][K][HW] 1/norm
#define WS_CAND_OFF (WS_INV_OFF + B_*K_*HW_)        // [B][N][NUM] int4
#define WS_GAP_OFF  (WS_CAND_OFF + B_*N_*NUM_*4)    // [B][N][NUM] float
#define WS_IDX_OFF  (WS_GAP_OFF + B_*N_*NUM_)       // [B][N][NUM] int
#define WS_A2_OFF   (WS_IDX_OFF + B_*N_*NUM_)       // [B][NUM][C] normed q
#define WS_GHI_OFF  (WS_A2_OFF + B_*NUM_*C_)        // pre-split planes
#define GPLANE_V4   (B_*K_*16*HW_)                  // u32x4 per plane

typedef __bf16 bf16x8 __attribute__((ext_vector_type(8)));
typedef float  f32x4  __attribute__((ext_vector_type(4)));
typedef unsigned int u32x4 __attribute__((ext_vector_type(4)));

static __device__ __forceinline__ f32x4 mf16(bf16x8 a, bf16x8 b, f32x4 c) {
    return __builtin_amdgcn_mfma_f32_16x16x32_bf16(a, b, c, 0, 0, 0);
}

// RTNE bf16 high-part (bit math, branch-free)
static __device__ __forceinline__ unsigned bfhi16(float x) {
    unsigned b = __float_as_uint(x);
    return (b + 0x7fffu + ((b >> 16) & 1u)) >> 16;
}
// split two floats (consecutive c) into packed hi-pair and lo-pair u32
static __device__ __forceinline__ void split2(float x, float y,
                                              unsigned &hp, unsigned &lp) {
    unsigned hx = bfhi16(x), hy = bfhi16(y);
    float rx = x - __uint_as_float(hx << 16);
    float ry = y - __uint_as_float(hy << 16);
    hp = hx | (hy << 16);
    lp = bfhi16(rx) | (bfhi16(ry) << 16);
}

// ---- contraction-proof mul/add (verbatim from the passing round-6 kernel)
static __device__ __forceinline__ float fmul_nc(float a, float b) {
    float r = a * b;
    asm volatile("" : "+v"(r));
    return r;
}
static __device__ __forceinline__ float fadd_nc(float a, float b) {
    float r = a + b;
    asm volatile("" : "+v"(r));
    return r;
}

// async global -> LDS, 16B per lane
static __device__ __forceinline__ void gll16(const u32x4* g, u32x4* l) {
    __builtin_amdgcn_global_load_lds(
        (const __attribute__((address_space(1))) void*)g,
        (__attribute__((address_space(3))) void*)l, 16, 0, 0);
}

// ---------------------------------------------------------------------------
// Kernel 1: per-(b,k,h) inverse L2 norm over c (fp32 guide values).
// ---------------------------------------------------------------------------
__global__ void norm_kernel(const float* __restrict__ refs,
                            float* __restrict__ inv) {
    int i = blockIdx.x * blockDim.x + threadIdx.x;   // over B*K*HW
    int h  = i & (HW_ - 1);
    int bk = i >> 12;
    const float* p = refs + (size_t)bk * C_ * HW_ + h;
    float ss = 0.f;
#pragma unroll 8
    for (int c = 0; c < C_; ++c) {
        float v = p[(size_t)c * HW_];
        ss = fmaf(v, v, ss);
    }
    inv[i] = 1.0f / fmaxf(sqrtf(ss), 1e-12f);
}

// ---------------------------------------------------------------------------
// Kernel 0: pre-split NORMALIZED refs into bf16 hi/lo pair planes:
// G[(bk*16+cg)*HW + h] = u32x4{pair of (ref[c][h]*inv[h]) for c=cg*8+2m..}.
// ---------------------------------------------------------------------------
__global__ void presplit_kernel(const float* __restrict__ refs,
                                const float* __restrict__ inv,
                                u32x4* __restrict__ Ghi,
                                u32x4* __restrict__ Glo) {
    int i = blockIdx.x * blockDim.x + threadIdx.x;   // over B*K*16*HW
    int h  = i & (HW_ - 1);
    int cg = (i >> 12) & 15;
    int bk = i >> 16;
    float iv = inv[bk * HW_ + h];
    const float* p = refs + ((size_t)bk * C_ + cg * 8) * HW_ + h;
    u32x4 H, L;
#pragma unroll
    for (int m = 0; m < 4; ++m) {
        float x = p[(size_t)(2 * m) * HW_] * iv;
        float y = p[(size_t)(2 * m + 1) * HW_] * iv;
        unsigned hp, lp;
        split2(x, y, hp, lp);
        H[m] = hp; L[m] = lp;
    }
    Ghi[i] = H;
    Glo[i] = L;
}

// ---------------------------------------------------------------------------
// Kernel 2: gather query vectors; write raw (A, for emul/fuse) and
// L2-normalized (A2, for the GEMM — per-q positive scale, argmax-invariant).
// One 64-lane wave per q-vector (2 c per lane).
// ---------------------------------------------------------------------------
__global__ void aprep2_kernel(const float* __restrict__ feat,
                              const int* __restrict__ fidx,
                              float* __restrict__ A,
                              float* __restrict__ A2) {
    int w    = (blockIdx.x * blockDim.x + threadIdx.x) >> 6;  // bq
    int lane = threadIdx.x & 63;
    int fi = fidx[w];
    int b  = w >> 11;
    const float* src = feat + (size_t)b * C_ * HW_ + fi;
    float v0 = src[(size_t)lane * HW_];
    float v1 = src[(size_t)(lane + 64) * HW_];
    float ss = fmaf(v0, v0, v1 * v1);
#pragma unroll
    for (int off = 32; off; off >>= 1) ss += __shfl_xor(ss, off);
    float rn = 1.0f / fmaxf(sqrtf(ss), 1e-12f);
    size_t o = (size_t)w * C_;
    A[o + lane]       = v0;
    A[o + lane + 64]  = v1;
    A2[o + lane]      = v0 * rn;
    A2[o + lane + 64] = v1 * rn;
}

// ---------------------------------------------------------------------------
// Kernel 3 (main): split-bf16 3-pass MFMA GEMM on normalized operands.
// acc init = 6.0 -> scores in [5,7] (one fp32 octave) -> packed u32 keys
//   key = ((bits & 0x7FFFF8) << 9) | h   (20 score bits + 12 index bits)
// branchless top-2 per lane per q-row; 16-lane bitonic merge -> top-4 keys.
// Staging via global_load_lds (async DMA), double-buffered, 1 barrier/iter;
// gll drain (vmcnt before barrier) ages behind the 48-MFMA phase.
// ---------------------------------------------------------------------------
__global__ __launch_bounds__(256, 4) void gemm_gll_topk(
        const float* __restrict__ A2,
        const u32x4* __restrict__ Ghi, const u32x4* __restrict__ Glo,
        const int* __restrict__ pindex,
        int4* __restrict__ cand4, float* __restrict__ gaps) {
    __shared__ u32x4 Bsh[2][2][512];   // 32 KiB: [buf][plane][cg*32+h]

    const int tid = threadIdx.x;
    const int l = tid & 63, wq = tid >> 6;
    const int ll = l & 15, lh = l >> 4;

    // XCD swizzle: 112 consecutive work-ids per XCD
    int bid = blockIdx.x;
    int swz = (bid & 7) * 112 + (bid >> 3);
    int pair = swz >> 4, qt = swz & 15;
    int b = pair / N_, n = pair % N_;
    int index = pindex[0];
    int ks = n + (n >= index ? 1 : 0);

    const float* Ap = A2 + ((size_t)b * NUM_ + qt * 128 + wq * 32) * C_;
    const u32x4* Gh = Ghi + (size_t)(b * K_ + ks) * 16 * HW_;
    const u32x4* Gl = Glo + (size_t)(b * K_ + ks) * 16 * HW_;

    // ---- A fragments (hi/lo split of normalized q), persistent ----
    bf16x8 ahi[2][4], alo[2][4];
#pragma unroll
    for (int mf = 0; mf < 2; ++mf)
#pragma unroll
        for (int kk = 0; kk < 4; ++kk) {
            const float* ap = Ap + (mf * 16 + ll) * C_ + kk * 32 + lh * 8;
            float4 xa = *(const float4*)ap;
            float4 xb = *(const float4*)(ap + 4);
            float xs[8] = {xa.x, xa.y, xa.z, xa.w, xb.x, xb.y, xb.z, xb.w};
            u32x4 H, L;
#pragma unroll
            for (int p = 0; p < 4; ++p) {
                unsigned hp, lp;
                split2(xs[2*p], xs[2*p+1], hp, lp);
                H[p] = hp; L[p] = lp;
            }
            ahi[mf][kk] = __builtin_bit_cast(bf16x8, H);
            alo[mf][kk] = __builtin_bit_cast(bf16x8, L);
        }

    // ---- per-lane packed-key top-2 per q-row (8 rows) ----
    unsigned k1[8], k2[8];
#pragma unroll
    for (int rw = 0; rw < 8; ++rw) { k1[rw] = 0u; k2[rw] = 0u; }

    // ---- gll staging map: call j stages linear idx j*256+tid ----
    const int lin0 = tid, lin1 = 256 + tid;
    const size_t go0 = (size_t)(lin0 >> 5) * HW_ + (lin0 & 31);
    const size_t go1 = (size_t)(lin1 >> 5) * HW_ + (lin1 & 31);

#define STAGE(buf, htv) do {                                   \
        gll16(Gh + go0 + (htv), &Bsh[buf][0][lin0]);           \
        gll16(Gh + go1 + (htv), &Bsh[buf][0][lin1]);           \
        gll16(Gl + go0 + (htv), &Bsh[buf][1][lin0]);           \
        gll16(Gl + go1 + (htv), &Bsh[buf][1][lin1]);           \
    } while (0)

    STAGE(0, 0);
    __syncthreads();   // vmcnt(0) drain inserted by compiler

    for (int t = 0; t < 128; ++t) {
        const int cur = t & 1;
        const int ht = t * 32;

        // issue next tile into the other buffer; ages behind MFMA below
        if (t < 127) STAGE(cur ^ 1, ht + 32);

        // ---- 3-pass MFMA: acc = 6 + Ah*Bh + Ah*Bl + Al*Bh ----
        f32x4 acc[2][2];
#pragma unroll
        for (int mf = 0; mf < 2; ++mf)
#pragma unroll
            for (int nf = 0; nf < 2; ++nf) acc[mf][nf] = 6.0f;

#pragma unroll
        for (int kk = 0; kk < 4; ++kk) {
#pragma unroll
            for (int nf = 0; nf < 2; ++nf) {
                int off = (kk * 4 + lh) * 32 + nf * 16 + ll;
                bf16x8 bh = __builtin_bit_cast(bf16x8, Bsh[cur][0][off]);
                bf16x8 bl = __builtin_bit_cast(bf16x8, Bsh[cur][1][off]);
#pragma unroll
                for (int mf = 0; mf < 2; ++mf) {
                    f32x4 a_ = acc[mf][nf];
                    a_ = mf16(ahi[mf][kk], bh, a_);
                    a_ = mf16(ahi[mf][kk], bl, a_);
                    a_ = mf16(alo[mf][kk], bh, a_);
                    acc[mf][nf] = a_;
                }
            }
        }

        // ---- packed-key top-2 (branchless, 5 VALU/elem) ----
#pragma unroll
        for (int nf = 0; nf < 2; ++nf) {
            unsigned hv = (unsigned)(ht + nf * 16 + ll);
#pragma unroll
            for (int mf = 0; mf < 2; ++mf)
#pragma unroll
                for (int r = 0; r < 4; ++r) {
                    int rw = mf * 4 + r;
                    unsigned u = __float_as_uint(acc[mf][nf][r]);
                    unsigned key = ((u & 0x007FFFF8u) << 9) | hv;
                    unsigned mn = min(k1[rw], key);
                    k1[rw] = max(k1[rw], key);
                    k2[rw] = max(k2[rw], mn);
                }
        }

        __syncthreads();   // next tile staged + all reads of cur done
    }
#undef STAGE

    // ---- 16-lane bitonic merge of (k1,k2) -> global top-4 keys ----
#define CEU(X,Y) { if (mv[Y] > mv[X]) { unsigned t_ = mv[X]; mv[X] = mv[Y]; mv[Y] = t_; } }
#pragma unroll
    for (int rw = 0; rw < 8; ++rw) {
        unsigned av[4] = {k1[rw], k2[rw], 0u, 0u};
#pragma unroll
        for (int s = 1; s <= 8; s <<= 1) {
            unsigned bv[4];
#pragma unroll
            for (int j = 0; j < 4; ++j)
                bv[j] = (unsigned)__shfl_xor((int)av[j], s);
            unsigned mv[4];
#pragma unroll
            for (int j = 0; j < 4; ++j)
                mv[j] = (av[j] > bv[3-j]) ? av[j] : bv[3-j];
            CEU(0, 2) CEU(1, 3) CEU(0, 1) CEU(2, 3)
#pragma unroll
            for (int j = 0; j < 4; ++j) av[j] = mv[j];
        }
        if (ll == 0) {
            int q = qt * 128 + wq * 32 + (rw >> 2) * 16 + lh * 4 + (rw & 3);
            size_t o = (size_t)(b * N_ + n) * NUM_ + q;
            cand4[o] = make_int4((int)(av[0] & 0xFFFu), (int)(av[1] & 0xFFFu),
                                 (int)(av[2] & 0xFFFu), (int)(av[3] & 0xFFFu));
            gaps[o]  = (float)((av[0] >> 12) - (av[1] >> 12));  // key units
        }
    }
#undef CEU
}

// ---------------------------------------------------------------------------
// numpy pairwise sum (n=128) — verbatim from the passing round-6 kernel.
// ---------------------------------------------------------------------------
static __device__ float pairwise128_sumsq_div(const float* __restrict__ x,
                                              float d) {
    float r[8];
#pragma unroll
    for (int j = 0; j < 8; ++j) {
        float v = __fdiv_rn(x[j], d);
        r[j] = fmul_nc(v, v);
    }
    for (int i = 8; i < C_; i += 8) {
#pragma unroll
        for (int j = 0; j < 8; ++j) {
            float v = __fdiv_rn(x[i + j], d);
            r[j] = fadd_nc(r[j], fmul_nc(v, v));
        }
    }
    return fadd_nc(fadd_nc(fadd_nc(r[0], r[1]), fadd_nc(r[2], r[3])),
                   fadd_nc(fadd_nc(r[4], r[5]), fadd_nc(r[6], r[7])));
}

// Emulated numpy score (verbatim from round 6 — all non-FMA where numpy is).
static __device__ float emul_score(const float* __restrict__ qp,
                                   const float* __restrict__ Rb,
                                   int h, float n1, float n2) {
    float rv0 = Rb[h];
    float sr = fmul_nc(rv0, rv0);
    for (int c = 1; c < C_; ++c) {
        float rv = Rb[(size_t)c * HW_ + h];
        sr = fadd_nc(sr, fmul_nc(rv, rv));
    }
    float nr = fmaxf(__fsqrt_rn(sr), 1e-12f);
    float acc = 0.f;
    for (int c = 0; c < C_; ++c) {
        float w2 = __fdiv_rn(__fdiv_rn(qp[c], n1), n2);
        float wr = __fdiv_rn(Rb[(size_t)c * HW_ + h], nr);
        acc = fadd_nc(acc, fmul_nc(w2, wr));
    }
    return acc;
}

// ---------------------------------------------------------------------------
// Kernel 3b: adjudicate top-4. Prune when gap (in key units, 1 unit=7.6e-6)
// is decisive; else exact numpy emulation, lowest-index tie-break.
// ---------------------------------------------------------------------------
__global__ void rescore_emul4(const float* __restrict__ A,
                              const float* __restrict__ refs,
                              const int* __restrict__ pindex,
                              const int4* __restrict__ cand4,
                              const float* __restrict__ gaps,
                              float thr,
                              int* __restrict__ idxout,
                              float* __restrict__ out2) {
    int r = blockIdx.x * blockDim.x + threadIdx.x;   // over B*N*NUM
    if (r >= B_ * N_ * NUM_) return;
    int4 cd = cand4[r];
    int win;
    if (gaps[r] > thr) {
        win = cd.x;
    } else {
        int q  = r & (NUM_ - 1);
        int bn = r >> 11;
        int b = bn / N_, n = bn % N_;
        int index = pindex[0];
        int ks = n + (n >= index ? 1 : 0);
        const float* qp = A    + ((size_t)b * NUM_ + q) * C_;
        const float* Rb = refs + (size_t)(b * K_ + ks) * C_ * HW_;
        float s1 = pairwise128_sumsq_div(qp, 1.0f);
        float n1 = fmaxf(__fsqrt_rn(s1), 1e-12f);
        float s2 = pairwise128_sumsq_div(qp, n1);
        float n2 = fmaxf(__fsqrt_rn(s2), 1e-12f);
        float sa = emul_score(qp, Rb, cd.x, n1, n2);
        float sb = emul_score(qp, Rb, cd.y, n1, n2);
        float sc = emul_score(qp, Rb, cd.z, n1, n2);
        float sd = emul_score(qp, Rb, cd.w, n1, n2);
        win = cd.x; float bw = sa;
        if (sb > bw || (sb == bw && cd.y < win)) { bw = sb; win = cd.y; }
        if (sc > bw || (sc == bw && cd.z < win)) { bw = sc; win = cd.z; }
        if (sd > bw || (sd == bw && cd.w < win)) { bw = sd; win = cd.w; }
    }
    idxout[r] = win;
    out2[r]   = (float)win;
}

// ---------------------------------------------------------------------------
// Kernel 4: fused = base_sim*feat_sel + sum_n sims[n]*refs[b,kn,:,idx_n],
// scattered into out[b][c][fi]. Also writes feat_indices output as float.
// ---------------------------------------------------------------------------
__global__ void fuse_scatter(const float* __restrict__ A,
                             const float* __restrict__ refs,
                             const float* __restrict__ sim,
                             const int* __restrict__ fidx,
                             const int* __restrict__ pindex,
                             const int* __restrict__ idxbuf,
                             float* __restrict__ out0,
                             float* __restrict__ out1) {
    int bq = blockIdx.x;                 // over B*NUM
    int q  = bq & (NUM_ - 1);
    int b  = bq >> 11;
    int c  = threadIdx.x;                // 128 threads
    int index = pindex[0];
    int fi = fidx[bq];

    float v = sim[b * K_ + index] * A[(size_t)bq * C_ + c];
#pragma unroll
    for (int n = 0; n < N_; ++n) {
        int ks = n + (n >= index ? 1 : 0);
        int id = idxbuf[(size_t)(b * N_ + n) * NUM_ + q];
        v = fmaf(sim[b * K_ + ks],
                 refs[((size_t)(b * K_ + ks) * C_ + c) * HW_ + id], v);
    }
    out0[((size_t)b * C_ + c) * HW_ + fi] = v;
    if (c == 0) out1[bq] = (float)fi;
}

// ---------------------------------------------------------------------------
extern "C" void kernel_launch(void* const* d_in, const int* in_sizes, int n_in,
                              void* d_out, int out_size, void* d_ws, size_t ws_size,
                              hipStream_t stream) {
    const float* feat = (const float*)d_in[0];   // [B][C][HW]
    const float* refs = (const float*)d_in[1];   // [B][K][C][HW]
    const float* sim  = (const float*)d_in[2];   // [B][K]
    const int*   fidx = (const int*)d_in[3];     // [B][NUM]
    const int*   pidx = (const int*)d_in[4];     // scalar index

    float* wsf   = (float*)d_ws;
    float* A     = wsf + WS_A_OFF;
    float* inv   = wsf + WS_INV_OFF;
    int4*  cand  = (int4*)(wsf + WS_CAND_OFF);
    float* gaps  = wsf + WS_GAP_OFF;
    int*   idxf  = (int*)(wsf + WS_IDX_OFF);
    float* A2    = wsf + WS_A2_OFF;
    u32x4* Ghi   = (u32x4*)(wsf + WS_GHI_OFF);
    u32x4* Glo   = Ghi + GPLANE_V4;

    float* out0 = (float*)d_out;                       // [B][C][HW]
    float* out1 = out0 + (size_t)B_ * C_ * HW_;        // feat_indices (f32)
    float* out2 = out1 + (size_t)B_ * NUM_;            // ref_indices (f32)

    norm_kernel<<<(B_ * K_ * HW_) / 256, 256, 0, stream>>>(refs, inv);
    aprep2_kernel<<<(B_ * NUM_) / 4, 256, 0, stream>>>(feat, fidx, A, A2);
    hipMemcpyAsync(out0, feat, (size_t)B_ * C_ * HW_ * sizeof(float),
                   hipMemcpyDeviceToDevice, stream);
    presplit_kernel<<<(B_ * K_ * 16 * HW_) / 256, 256, 0, stream>>>(
        refs, inv, Ghi, Glo);
    gemm_gll_topk<<<56 * 16, 256, 0, stream>>>(A2, Ghi, Glo, pidx,
                                               cand, gaps);
    // prune threshold: 8 key units ~ 6e-5 in cosine scale
    rescore_emul4<<<(B_ * N_ * NUM_ + 255) / 256, 256, 0, stream>>>(
        A, refs, pidx, cand, gaps, 8.5f, idxf, out2);
    fuse_scatter<<<B_ * NUM_, 128, 0, stream>>>(A, refs, sim, fidx, pidx,
                                                idxf, out0, out1);
}

// Round 11
// 702.314 us; speedup vs baseline: 4.6154x; 1.3525x over previous
//
#include <hip/hip_runtime.h>
#include <math.h>

#define B_    8
#define K_    8
#define C_    128
#define HW_   4096
#define NUM_  2048
#define N_    7          // K-1 refs used

// ---------------- workspace layout (32-bit words) ----------------
#define WS_A_OFF    0                               // [B][NUM][C] raw q
#define WS_INV_OFF  (B_*NUM_*C_)                    // [B][K][HW] 1/norm
#define WS_CAND_OFF (WS_INV_OFF + B_*K_*HW_)        // [B][N][NUM] int4
#define WS_GAP_OFF  (WS_CAND_OFF + B_*N_*NUM_*4)    // [B][N][NUM] float
#define WS_IDX_OFF  (WS_GAP_OFF + B_*N_*NUM_)       // [B][N][NUM] int
#define WS_A2_OFF   (WS_IDX_OFF + B_*N_*NUM_)       // [B][NUM][C] normed q
#define WS_GHI_OFF  (WS_A2_OFF + B_*NUM_*C_)        // pre-split planes
#define GPLANE_V4   (B_*K_*16*HW_)                  // u32x4 per plane

typedef __bf16 bf16x8 __attribute__((ext_vector_type(8)));
typedef float  f32x4  __attribute__((ext_vector_type(4)));
typedef unsigned int u32x4 __attribute__((ext_vector_type(4)));

static __device__ __forceinline__ f32x4 mf16(bf16x8 a, bf16x8 b, f32x4 c) {
    return __builtin_amdgcn_mfma_f32_16x16x32_bf16(a, b, c, 0, 0, 0);
}

// RTNE bf16 high-part (bit math, branch-free)
static __device__ __forceinline__ unsigned bfhi16(float x) {
    unsigned b = __float_as_uint(x);
    return (b + 0x7fffu + ((b >> 16) & 1u)) >> 16;
}
// split two floats (consecutive c) into packed hi-pair and lo-pair u32
static __device__ __forceinline__ void split2(float x, float y,
                                              unsigned &hp, unsigned &lp) {
    unsigned hx = bfhi16(x), hy = bfhi16(y);
    float rx = x - __uint_as_float(hx << 16);
    float ry = y - __uint_as_float(hy << 16);
    hp = hx | (hy << 16);
    lp = bfhi16(rx) | (bfhi16(ry) << 16);
}

// ---- contraction-proof mul/add (verbatim from the passing round-6 kernel)
static __device__ __forceinline__ float fmul_nc(float a, float b) {
    float r = a * b;
    asm volatile("" : "+v"(r));
    return r;
}
static __device__ __forceinline__ float fadd_nc(float a, float b) {
    float r = a + b;
    asm volatile("" : "+v"(r));
    return r;
}

// async global -> LDS, 16B per lane
static __device__ __forceinline__ void gll16(const u32x4* g, u32x4* l) {
    __builtin_amdgcn_global_load_lds(
        (const __attribute__((address_space(1))) void*)g,
        (__attribute__((address_space(3))) void*)l, 16, 0, 0);
}

// ---------------------------------------------------------------------------
// Kernel 1: per-(b,k,h) inverse L2 norm over c (fp32 guide values).
// ---------------------------------------------------------------------------
__global__ void norm_kernel(const float* __restrict__ refs,
                            float* __restrict__ inv) {
    int i = blockIdx.x * blockDim.x + threadIdx.x;   // over B*K*HW
    int h  = i & (HW_ - 1);
    int bk = i >> 12;
    const float* p = refs + (size_t)bk * C_ * HW_ + h;
    float ss = 0.f;
#pragma unroll 8
    for (int c = 0; c < C_; ++c) {
        float v = p[(size_t)c * HW_];
        ss = fmaf(v, v, ss);
    }
    inv[i] = 1.0f / fmaxf(sqrtf(ss), 1e-12f);
}

// ---------------------------------------------------------------------------
// Kernel 0: pre-split NORMALIZED refs into bf16 hi/lo pair planes:
// G[(bk*16+cg)*HW + h] = u32x4{pair of (ref[c][h]*inv[h]) for c=cg*8+2m..}.
// ---------------------------------------------------------------------------
__global__ void presplit_kernel(const float* __restrict__ refs,
                                const float* __restrict__ inv,
                                u32x4* __restrict__ Ghi,
                                u32x4* __restrict__ Glo) {
    int i = blockIdx.x * blockDim.x + threadIdx.x;   // over B*K*16*HW
    int h  = i & (HW_ - 1);
    int cg = (i >> 12) & 15;
    int bk = i >> 16;
    float iv = inv[bk * HW_ + h];
    const float* p = refs + ((size_t)bk * C_ + cg * 8) * HW_ + h;
    u32x4 H, L;
#pragma unroll
    for (int m = 0; m < 4; ++m) {
        float x = p[(size_t)(2 * m) * HW_] * iv;
        float y = p[(size_t)(2 * m + 1) * HW_] * iv;
        unsigned hp, lp;
        split2(x, y, hp, lp);
        H[m] = hp; L[m] = lp;
    }
    Ghi[i] = H;
    Glo[i] = L;
}

// ---------------------------------------------------------------------------
// Kernel 2: gather query vectors; write raw (A, for emul/fuse) and
// L2-normalized (A2, for the GEMM — per-q positive scale, argmax-invariant).
// ---------------------------------------------------------------------------
__global__ void aprep2_kernel(const float* __restrict__ feat,
                              const int* __restrict__ fidx,
                              float* __restrict__ A,
                              float* __restrict__ A2) {
    int w    = (blockIdx.x * blockDim.x + threadIdx.x) >> 6;  // bq
    int lane = threadIdx.x & 63;
    int fi = fidx[w];
    int b  = w >> 11;
    const float* src = feat + (size_t)b * C_ * HW_ + fi;
    float v0 = src[(size_t)lane * HW_];
    float v1 = src[(size_t)(lane + 64) * HW_];
    float ss = fmaf(v0, v0, v1 * v1);
#pragma unroll
    for (int off = 32; off; off >>= 1) ss += __shfl_xor(ss, off);
    float rn = 1.0f / fmaxf(sqrtf(ss), 1e-12f);
    size_t o = (size_t)w * C_;
    A[o + lane]       = v0;
    A[o + lane + 64]  = v1;
    A2[o + lane]      = v0 * rn;
    A2[o + lane + 64] = v1 * rn;
}

// ---------------------------------------------------------------------------
// Kernel 3 (main): split-bf16 3-pass MFMA GEMM on normalized operands.
// (verbatim from passing round 10)
// ---------------------------------------------------------------------------
__global__ __launch_bounds__(256, 4) void gemm_gll_topk(
        const float* __restrict__ A2,
        const u32x4* __restrict__ Ghi, const u32x4* __restrict__ Glo,
        const int* __restrict__ pindex,
        int4* __restrict__ cand4, float* __restrict__ gaps) {
    __shared__ u32x4 Bsh[2][2][512];   // 32 KiB: [buf][plane][cg*32+h]

    const int tid = threadIdx.x;
    const int l = tid & 63, wq = tid >> 6;
    const int ll = l & 15, lh = l >> 4;

    // XCD swizzle: 112 consecutive work-ids per XCD
    int bid = blockIdx.x;
    int swz = (bid & 7) * 112 + (bid >> 3);
    int pair = swz >> 4, qt = swz & 15;
    int b = pair / N_, n = pair % N_;
    int index = pindex[0];
    int ks = n + (n >= index ? 1 : 0);

    const float* Ap = A2 + ((size_t)b * NUM_ + qt * 128 + wq * 32) * C_;
    const u32x4* Gh = Ghi + (size_t)(b * K_ + ks) * 16 * HW_;
    const u32x4* Gl = Glo + (size_t)(b * K_ + ks) * 16 * HW_;

    // ---- A fragments (hi/lo split of normalized q), persistent ----
    bf16x8 ahi[2][4], alo[2][4];
#pragma unroll
    for (int mf = 0; mf < 2; ++mf)
#pragma unroll
        for (int kk = 0; kk < 4; ++kk) {
            const float* ap = Ap + (mf * 16 + ll) * C_ + kk * 32 + lh * 8;
            float4 xa = *(const float4*)ap;
            float4 xb = *(const float4*)(ap + 4);
            float xs[8] = {xa.x, xa.y, xa.z, xa.w, xb.x, xb.y, xb.z, xb.w};
            u32x4 H, L;
#pragma unroll
            for (int p = 0; p < 4; ++p) {
                unsigned hp, lp;
                split2(xs[2*p], xs[2*p+1], hp, lp);
                H[p] = hp; L[p] = lp;
            }
            ahi[mf][kk] = __builtin_bit_cast(bf16x8, H);
            alo[mf][kk] = __builtin_bit_cast(bf16x8, L);
        }

    // ---- per-lane packed-key top-2 per q-row (8 rows) ----
    unsigned k1[8], k2[8];
#pragma unroll
    for (int rw = 0; rw < 8; ++rw) { k1[rw] = 0u; k2[rw] = 0u; }

    // ---- gll staging map: call j stages linear idx j*256+tid ----
    const int lin0 = tid, lin1 = 256 + tid;
    const size_t go0 = (size_t)(lin0 >> 5) * HW_ + (lin0 & 31);
    const size_t go1 = (size_t)(lin1 >> 5) * HW_ + (lin1 & 31);

#define STAGE(buf, htv) do {                                   \
        gll16(Gh + go0 + (htv), &Bsh[buf][0][lin0]);           \
        gll16(Gh + go1 + (htv), &Bsh[buf][0][lin1]);           \
        gll16(Gl + go0 + (htv), &Bsh[buf][1][lin0]);           \
        gll16(Gl + go1 + (htv), &Bsh[buf][1][lin1]);           \
    } while (0)

    STAGE(0, 0);
    __syncthreads();   // vmcnt(0) drain inserted by compiler

    for (int t = 0; t < 128; ++t) {
        const int cur = t & 1;
        const int ht = t * 32;

        // issue next tile into the other buffer; ages behind MFMA below
        if (t < 127) STAGE(cur ^ 1, ht + 32);

        // ---- 3-pass MFMA: acc = 6 + Ah*Bh + Ah*Bl + Al*Bh ----
        f32x4 acc[2][2];
#pragma unroll
        for (int mf = 0; mf < 2; ++mf)
#pragma unroll
            for (int nf = 0; nf < 2; ++nf) acc[mf][nf] = 6.0f;

#pragma unroll
        for (int kk = 0; kk < 4; ++kk) {
#pragma unroll
            for (int nf = 0; nf < 2; ++nf) {
                int off = (kk * 4 + lh) * 32 + nf * 16 + ll;
                bf16x8 bh = __builtin_bit_cast(bf16x8, Bsh[cur][0][off]);
                bf16x8 bl = __builtin_bit_cast(bf16x8, Bsh[cur][1][off]);
#pragma unroll
                for (int mf = 0; mf < 2; ++mf) {
                    f32x4 a_ = acc[mf][nf];
                    a_ = mf16(ahi[mf][kk], bh, a_);
                    a_ = mf16(ahi[mf][kk], bl, a_);
                    a_ = mf16(alo[mf][kk], bh, a_);
                    acc[mf][nf] = a_;
                }
            }
        }

        // ---- packed-key top-2 (branchless, 5 VALU/elem) ----
#pragma unroll
        for (int nf = 0; nf < 2; ++nf) {
            unsigned hv = (unsigned)(ht + nf * 16 + ll);
#pragma unroll
            for (int mf = 0; mf < 2; ++mf)
#pragma unroll
                for (int r = 0; r < 4; ++r) {
                    int rw = mf * 4 + r;
                    unsigned u = __float_as_uint(acc[mf][nf][r]);
                    unsigned key = ((u & 0x007FFFF8u) << 9) | hv;
                    unsigned mn = min(k1[rw], key);
                    k1[rw] = max(k1[rw], key);
                    k2[rw] = max(k2[rw], mn);
                }
        }

        __syncthreads();   // next tile staged + all reads of cur done
    }
#undef STAGE

    // ---- 16-lane bitonic merge of (k1,k2) -> global top-4 keys ----
#define CEU(X,Y) { if (mv[Y] > mv[X]) { unsigned t_ = mv[X]; mv[X] = mv[Y]; mv[Y] = t_; } }
#pragma unroll
    for (int rw = 0; rw < 8; ++rw) {
        unsigned av[4] = {k1[rw], k2[rw], 0u, 0u};
#pragma unroll
        for (int s = 1; s <= 8; s <<= 1) {
            unsigned bv[4];
#pragma unroll
            for (int j = 0; j < 4; ++j)
                bv[j] = (unsigned)__shfl_xor((int)av[j], s);
            unsigned mv[4];
#pragma unroll
            for (int j = 0; j < 4; ++j)
                mv[j] = (av[j] > bv[3-j]) ? av[j] : bv[3-j];
            CEU(0, 2) CEU(1, 3) CEU(0, 1) CEU(2, 3)
#pragma unroll
            for (int j = 0; j < 4; ++j) av[j] = mv[j];
        }
        if (ll == 0) {
            int q = qt * 128 + wq * 32 + (rw >> 2) * 16 + lh * 4 + (rw & 3);
            size_t o = (size_t)(b * N_ + n) * NUM_ + q;
            cand4[o] = make_int4((int)(av[0] & 0xFFFu), (int)(av[1] & 0xFFFu),
                                 (int)(av[2] & 0xFFFu), (int)(av[3] & 0xFFFu));
            gaps[o]  = (float)((av[0] >> 12) - (av[1] >> 12));  // key units
        }
    }
#undef CEU
}

// ---------------------------------------------------------------------------
// numpy pairwise sum (n=128) — verbatim rounding from the passing round-6
// kernel.
// ---------------------------------------------------------------------------
static __device__ float pairwise128_sumsq_div(const float* __restrict__ x,
                                              float d) {
    float r[8];
#pragma unroll
    for (int j = 0; j < 8; ++j) {
        float v = __fdiv_rn(x[j], d);
        r[j] = fmul_nc(v, v);
    }
    for (int i = 8; i < C_; i += 8) {
#pragma unroll
        for (int j = 0; j < 8; ++j) {
            float v = __fdiv_rn(x[i + j], d);
            r[j] = fadd_nc(r[j], fmul_nc(v, v));
        }
    }
    return fadd_nc(fadd_nc(fadd_nc(r[0], r[1]), fadd_nc(r[2], r[3])),
                   fadd_nc(fadd_nc(r[4], r[5]), fadd_nc(r[6], r[7])));
}

// ---------------------------------------------------------------------------
// Emulated numpy score — ARITHMETIC VERBATIM from round 6, but the ref
// column is batch-loaded into a register array BEFORE any chain op, so the
// 128 scattered loads issue as one batch (one L3 latency) instead of being
// serialized between the volatile-asm chain ops (round-10's 390 µs tail).
// ---------------------------------------------------------------------------
static __device__ float emul_score_batched(const float* __restrict__ w2a,
                                           const float* __restrict__ Rb,
                                           int h) {
    float rv[C_];
#pragma unroll
    for (int c = 0; c < C_; ++c) rv[c] = Rb[(size_t)c * HW_ + h];
    float sr = fmul_nc(rv[0], rv[0]);
#pragma unroll
    for (int c = 1; c < C_; ++c)
        sr = fadd_nc(sr, fmul_nc(rv[c], rv[c]));    // non-FMA, ascending c
    float nr = fmaxf(__fsqrt_rn(sr), 1e-12f);
    float acc = 0.f;
#pragma unroll
    for (int c = 0; c < C_; ++c) {
        float wr = __fdiv_rn(rv[c], nr);
        acc = fadd_nc(acc, fmul_nc(w2a[c], wr));    // non-FMA, ascending c
    }
    return acc;
}

// ---------------------------------------------------------------------------
// Kernel 3b: adjudicate top-4. Prune when gap (key units) is decisive; else
// exact numpy emulation, lowest-index tie-break. w2 vector hoisted once per
// row (shared by all 4 candidates; identical __fdiv_rn rounding).
// ---------------------------------------------------------------------------
__global__ __launch_bounds__(256, 1) void rescore_emul4(
        const float* __restrict__ A,
        const float* __restrict__ refs,
        const int* __restrict__ pindex,
        const int4* __restrict__ cand4,
        const float* __restrict__ gaps,
        float thr,
        int* __restrict__ idxout,
        float* __restrict__ out2) {
    int r = blockIdx.x * blockDim.x + threadIdx.x;   // over B*N*NUM
    if (r >= B_ * N_ * NUM_) return;
    int4 cd = cand4[r];
    int win;
    if (gaps[r] > thr) {
        win = cd.x;
    } else {
        int q  = r & (NUM_ - 1);
        int bn = r >> 11;
        int b = bn / N_, n = bn % N_;
        int index = pindex[0];
        int ks = n + (n >= index ? 1 : 0);
        const float* qp = A    + ((size_t)b * NUM_ + q) * C_;
        const float* Rb = refs + (size_t)(b * K_ + ks) * C_ * HW_;
        float s1 = pairwise128_sumsq_div(qp, 1.0f);
        float n1 = fmaxf(__fsqrt_rn(s1), 1e-12f);
        float s2 = pairwise128_sumsq_div(qp, n1);
        float n2 = fmaxf(__fsqrt_rn(s2), 1e-12f);
        // hoist double-normalized query (verbatim rounding), reuse 4x
        float w2a[C_];
#pragma unroll
        for (int c = 0; c < C_; ++c)
            w2a[c] = __fdiv_rn(__fdiv_rn(qp[c], n1), n2);
        float sa = emul_score_batched(w2a, Rb, cd.x);
        float sb = emul_score_batched(w2a, Rb, cd.y);
        float sc = emul_score_batched(w2a, Rb, cd.z);
        float sd = emul_score_batched(w2a, Rb, cd.w);
        win = cd.x; float bw = sa;
        if (sb > bw || (sb == bw && cd.y < win)) { bw = sb; win = cd.y; }
        if (sc > bw || (sc == bw && cd.z < win)) { bw = sc; win = cd.z; }
        if (sd > bw || (sd == bw && cd.w < win)) { bw = sd; win = cd.w; }
    }
    idxout[r] = win;
    out2[r]   = (float)win;
}

// ---------------------------------------------------------------------------
// Kernel 4: fused = base_sim*feat_sel + sum_n sims[n]*refs[b,kn,:,idx_n],
// scattered into out[b][c][fi]. Also writes feat_indices output as float.
// ---------------------------------------------------------------------------
__global__ void fuse_scatter(const float* __restrict__ A,
                             const float* __restrict__ refs,
                             const float* __restrict__ sim,
                             const int* __restrict__ fidx,
                             const int* __restrict__ pindex,
                             const int* __restrict__ idxbuf,
                             float* __restrict__ out0,
                             float* __restrict__ out1) {
    int bq = blockIdx.x;                 // over B*NUM
    int q  = bq & (NUM_ - 1);
    int b  = bq >> 11;
    int c  = threadIdx.x;                // 128 threads
    int index = pindex[0];
    int fi = fidx[bq];

    float v = sim[b * K_ + index] * A[(size_t)bq * C_ + c];
#pragma unroll
    for (int n = 0; n < N_; ++n) {
        int ks = n + (n >= index ? 1 : 0);
        int id = idxbuf[(size_t)(b * N_ + n) * NUM_ + q];
        v = fmaf(sim[b * K_ + ks],
                 refs[((size_t)(b * K_ + ks) * C_ + c) * HW_ + id], v);
    }
    out0[((size_t)b * C_ + c) * HW_ + fi] = v;
    if (c == 0) out1[bq] = (float)fi;
}

// ---------------------------------------------------------------------------
extern "C" void kernel_launch(void* const* d_in, const int* in_sizes, int n_in,
                              void* d_out, int out_size, void* d_ws, size_t ws_size,
                              hipStream_t stream) {
    const float* feat = (const float*)d_in[0];   // [B][C][HW]
    const float* refs = (const float*)d_in[1];   // [B][K][C][HW]
    const float* sim  = (const float*)d_in[2];   // [B][K]
    const int*   fidx = (const int*)d_in[3];     // [B][NUM]
    const int*   pidx = (const int*)d_in[4];     // scalar index

    float* wsf   = (float*)d_ws;
    float* A     = wsf + WS_A_OFF;
    float* inv   = wsf + WS_INV_OFF;
    int4*  cand  = (int4*)(wsf + WS_CAND_OFF);
    float* gaps  = wsf + WS_GAP_OFF;
    int*   idxf  = (int*)(wsf + WS_IDX_OFF);
    float* A2    = wsf + WS_A2_OFF;
    u32x4* Ghi   = (u32x4*)(wsf + WS_GHI_OFF);
    u32x4* Glo   = Ghi + GPLANE_V4;

    float* out0 = (float*)d_out;                       // [B][C][HW]
    float* out1 = out0 + (size_t)B_ * C_ * HW_;        // feat_indices (f32)
    float* out2 = out1 + (size_t)B_ * NUM_;            // ref_indices (f32)

    norm_kernel<<<(B_ * K_ * HW_) / 256, 256, 0, stream>>>(refs, inv);
    aprep2_kernel<<<(B_ * NUM_) / 4, 256, 0, stream>>>(feat, fidx, A, A2);
    hipMemcpyAsync(out0, feat, (size_t)B_ * C_ * HW_ * sizeof(float),
                   hipMemcpyDeviceToDevice, stream);
    presplit_kernel<<<(B_ * K_ * 16 * HW_) / 256, 256, 0, stream>>>(
        refs, inv, Ghi, Glo);
    gemm_gll_topk<<<56 * 16, 256, 0, stream>>>(A2, Ghi, Glo, pidx,
                                               cand, gaps);
    // prune threshold: 8 key units ~ 6e-5 in cosine scale
    rescore_emul4<<<(B_ * N_ * NUM_ + 255) / 256, 256, 0, stream>>>(
        A, refs, pidx, cand, gaps, 8.5f, idxf, out2);
    fuse_scatter<<<B_ * NUM_, 128, 0, stream>>>(A, refs, sim, fidx, pidx,
                                                idxf, out0, out1);
}